// Round 12
// baseline (505.573 us; speedup 1.0000x reference)
//
#include <hip/hip_runtime.h>

// ---------------------------------------------------------------------------
// MultiHeadPooledSelfAttention on gfx950.
// R20 = R19 + Q-residual folding + mode-5 split-K x4:
//   (Q + attn)·Wd^T = attn·Wd^T + x·(Wd·Wq)^T + Wd·bq  ->  Q is never
//   materialized. Mode-0 shrinks to N=8192 (PQ|PK). New: mode-7 (Wdq=Wd·Wq
//   fold, KLEN=4096, mode-6-style rotated B staging), mode-8 (xres=x·Wdq^T,
//   f32 partial), bdq=bd+Wd·bq in cls_fold, reduce3 applies xres+bdq to
//   spatial rows only. Mode-4 epilogue drops the residual read.
//   Mode-5: split-K 2->4 (264->528 blocks; 4 f32 partials alias PQ exactly).
// Keeps: Wc=Wp·W fold (mode-6), wave-parallel cls_fold, PVt mode-2, BK=64
// staging XOR swizzle, bias via acc-init, XCD grouping, wave softmax,
// permuted token order (cls at index 1024).
// ---------------------------------------------------------------------------

typedef unsigned short u16;
typedef __attribute__((ext_vector_type(8))) short short8;   // 8 x bf16
typedef __attribute__((ext_vector_type(4))) float floatx4;
typedef __attribute__((ext_vector_type(4))) unsigned short us4;

__device__ __forceinline__ u16 f2bf(float f) {
  union { float f; unsigned u; } x; x.f = f;
  unsigned r = (x.u + 0x7fffu + ((x.u >> 16) & 1u)) >> 16;
  return (u16)r;
}
__device__ __forceinline__ float bf2f(u16 u) {
  union { unsigned u; float f; } x; x.u = ((unsigned)u) << 16;
  return x.f;
}

__device__ __forceinline__ void gld_lds16(const void* g, void* l) {
  __builtin_amdgcn_global_load_lds(
      (const __attribute__((address_space(1))) void*)g,
      (__attribute__((address_space(3))) void*)l, 16, 0, 0);
}

// ---------------------------------------------------------------------------
struct CvtArgs { const float* src[8]; u16* dst[8]; int n4[8]; };

__global__ __launch_bounds__(256) void cvt_all(CvtArgs a, int total4, float* __restrict__ e) {
  int t = blockIdx.x * 256 + threadIdx.x;
  if (t >= total4) {
    int et = (t - total4) * 4;                  // emb flat base, < 1024*512
    if (et >= 1024 * 512) return;
#pragma unroll
    for (int u = 0; u < 4; ++u) {
      int idx = et + u;
      int c = idx & 511, sp = idx >> 9;
      int y = sp >> 5, xg = sp & 31;
      int j = c & 127, seg = c >> 7;
      float omega = expf(-(float)j * (9.210340371976184f / 128.f));
      float arg = (float)((seg < 2) ? y : xg) * omega;
      e[idx] = (seg & 1) ? cosf(arg) : sinf(arg);
    }
    return;
  }
#pragma unroll
  for (int s = 0; s < 8; ++s) {
    if (t < a.n4[s]) {
      const float* sp = a.src[s] + (long)t * 4;
      u16* dp = a.dst[s] + (long)t * 4;
      float4 v = *(const float4*)sp;
      dp[0] = f2bf(v.x); dp[1] = f2bf(v.y); dp[2] = f2bf(v.z); dp[3] = f2bf(v.w);
      return;
    }
    t -= a.n4[s];
  }
}

// ---------------------------------------------------------------------------
// cls_fold (wave-parallel): one WAVE per dot.
//  wid < 12288 : cls rows Q/K/V_cls[b][o2] -> PQ/PK row 1024, PVt col 1024.
//  wid < 24576 : folded pool bias bc[t2] = Wp[o,:]·b[n*512..] + bp[o].
//  wid < 25088 : bdq[o] = bd[o] + Wd[o,:]·bq  (Q-residual bias fold, K=4096).
// Lane l loads elems l*8.. (coalesced); shfl_xor reduce.
// Grid: 6272 blocks x 256 (4 waves/block, 25088 waves).
// ---------------------------------------------------------------------------
struct CF {
  const u16* W;      // Wqb|Wkb|Wvb contiguous
  const u16* Wp;     // Wpqb|Wpkb|Wpvb contiguous
  const u16* Wdbp;   // Wdb (512 x 4096)
  const u16* xb;
  const float *bq, *bk, *bv, *bpq, *bpk, *bpv, *bd;
  u16 *PQ, *PK, *PVt;
  float* bc;
  float* bdq;
};

__global__ __launch_bounds__(256) void cls_fold(CF a) {
  int wid = blockIdx.x * 4 + (threadIdx.x >> 6);   // 0..25087
  int lane = threadIdx.x & 63;
  if (wid < 12288) {
    int mat = wid >> 12, o2 = wid & 4095, n = o2 >> 9, ch = o2 & 511;
    short8 wv = *(const short8*)(a.W + (long)wid * 512 + lane * 8);
    float wf[8];
#pragma unroll
    for (int e = 0; e < 8; ++e) wf[e] = bf2f((u16)wv[e]);
    float ac[4] = {0.f, 0.f, 0.f, 0.f};
#pragma unroll
    for (int b = 0; b < 4; ++b) {
      short8 xv = *(const short8*)(a.xb + ((long)b * 1025) * 512 + lane * 8);
#pragma unroll
      for (int e = 0; e < 8; ++e) ac[b] += wf[e] * bf2f((u16)xv[e]);
    }
#pragma unroll
    for (int o = 32; o > 0; o >>= 1)
#pragma unroll
      for (int b = 0; b < 4; ++b) ac[b] += __shfl_xor(ac[b], o, 64);
    if (lane == 0) {
      const float* bsrc = (mat == 0) ? a.bq : (mat == 1) ? a.bk : a.bv;
      float bias = bsrc[o2];
#pragma unroll
      for (int b = 0; b < 4; ++b) {
        long bn = b * 8 + n;
        u16 v = f2bf(ac[b] + bias);
        if (mat == 0)      a.PQ[(bn * 1025 + 1024) * 512 + ch] = v;
        else if (mat == 1) a.PK[(bn * 1025 + 1024) * 512 + ch] = v;
        else               a.PVt[(bn * 512 + ch) * 1088 + 1024] = v;
      }
    }
  } else if (wid < 24576) {
    int t2 = wid - 12288;
    int mat = t2 >> 12, o2 = t2 & 4095, n = o2 >> 9, o = o2 & 511;
    const float* bsrc = (mat == 0) ? a.bq : (mat == 1) ? a.bk : a.bv;
    short8 wp = *(const short8*)(a.Wp + (long)mat * 262144 + o * 512 + lane * 8);
    const float* bb = bsrc + n * 512 + lane * 8;
    float4 b0 = *(const float4*)bb;
    float4 b1 = *(const float4*)(bb + 4);
    float bf8[8] = {b0.x, b0.y, b0.z, b0.w, b1.x, b1.y, b1.z, b1.w};
    float s = 0.f;
#pragma unroll
    for (int e = 0; e < 8; ++e) s += bf2f((u16)wp[e]) * bf8[e];
#pragma unroll
    for (int o1 = 32; o1 > 0; o1 >>= 1) s += __shfl_xor(s, o1, 64);
    if (lane == 0) {
      const float* bpp = (mat == 0) ? a.bpq : (mat == 1) ? a.bpk : a.bpv;
      a.bc[t2] = s + bpp[o];
    }
  } else {
    int o = wid - 24576;                 // 0..511
    float s = 0.f;
    for (int c8 = 0; c8 < 8; ++c8) {
      int base = c8 * 512 + lane * 8;
      short8 wv = *(const short8*)(a.Wdbp + (long)o * 4096 + base);
      float4 b0 = *(const float4*)(a.bq + base);
      float4 b1 = *(const float4*)(a.bq + base + 4);
      float bf8[8] = {b0.x, b0.y, b0.z, b0.w, b1.x, b1.y, b1.z, b1.w};
#pragma unroll
      for (int e = 0; e < 8; ++e) s += bf2f((u16)wv[e]) * bf8[e];
    }
#pragma unroll
    for (int o1 = 32; o1 > 0; o1 >>= 1) s += __shfl_xor(s, o1, 64);
    if (lane == 0) a.bdq[o] = a.bd[o] + s;
  }
}

// ---------------------------------------------------------------------------
// S edge (permuted order: cls = index 1024): S[1024][kv] kv<=1024 and
// S[q][1024] q<1024 -> 2049 dots of length 512 per head. One dot per thread.
// ---------------------------------------------------------------------------
__global__ __launch_bounds__(256) void s_edge(const u16* __restrict__ PQ,
                                              const u16* __restrict__ PK,
                                              u16* __restrict__ S, int nh) {
  int flat = blockIdx.x;                 // nh*8
  int head, seg;
  if (nh == 32) {
    int xcd = flat & 7, s = flat >> 3;   // s: 0..31
    head = xcd + 8 * (s >> 3);           // 0..31
    seg = s & 7;
  } else {
    head = flat >> 3;
    seg = flat & 7;
  }
  const u16* pq = PQ + (long)head * 1025 * 512;
  const u16* pk = PK + (long)head * 1025 * 512;
  u16* sh = S + (long)head * 1025 * 1088;
#pragma unroll
  for (int i = 0; i < 2; ++i) {
    int local = i * 256 + (int)threadIdx.x;
    if (local >= 257) continue;
    int e = seg * 257 + local;
    if (e >= 2049) continue;
    int q, kv;
    if (e < 1025) { q = 1024; kv = e; }
    else { q = e - 1025; kv = 1024; }
    const u16* a = pq + (long)q * 512;
    const u16* b = pk + (long)kv * 512;
    float acc = 0.f;
    for (int k8 = 0; k8 < 64; ++k8) {
      short8 av = *(const short8*)(a + k8 * 8);
      short8 bv = *(const short8*)(b + k8 * 8);
#pragma unroll
      for (int u = 0; u < 8; ++u) acc += bf2f((u16)av[u]) * bf2f((u16)bv[u]);
    }
    sh[(long)q * 1088 + kv] = f2bf(acc * 0.04419417382415922f);
  }
}

// ---------------------------------------------------------------------------
// Softmax: one WAVE per row, 4 rows/block. XCD head-grouped.
// ---------------------------------------------------------------------------
__global__ __launch_bounds__(256) void softmax_rows(u16* __restrict__ S) {
  int flat = blockIdx.x;
  int xcd = flat & 7, s0 = flat >> 3;
  int zi = s0 / 257, blk = s0 - zi * 257;
  int head = xcd + 8 * zi;
  int wv = threadIdx.x >> 6, lane = threadIdx.x & 63;
  int row_i = blk * 4 + wv;
  if (row_i > 1024) return;
  u16* row = S + ((long)head * 1025 + row_i) * 1088;
  float v[16];
  float mx = -1e30f;
#pragma unroll
  for (int i = 0; i < 4; ++i) {
    us4 p = *(const us4*)(row + i * 256 + lane * 4);
#pragma unroll
    for (int e = 0; e < 4; ++e) { v[i * 4 + e] = bf2f(p[e]); mx = fmaxf(mx, v[i * 4 + e]); }
  }
  float e1024 = (lane == 0) ? bf2f(row[1024]) : -1e30f;
  mx = fmaxf(mx, e1024);
  for (int o = 32; o > 0; o >>= 1) mx = fmaxf(mx, __shfl_xor(mx, o, 64));
  float s = 0.f;
#pragma unroll
  for (int i = 0; i < 16; ++i) { v[i] = __expf(v[i] - mx); s += v[i]; }
  e1024 = (lane == 0) ? __expf(e1024 - mx) : 0.f;
  s += e1024;
  for (int o = 32; o > 0; o >>= 1) s += __shfl_xor(s, o, 64);
  float inv = 1.0f / s;
#pragma unroll
  for (int i = 0; i < 4; ++i) {
    us4 q;
#pragma unroll
    for (int e = 0; e < 4; ++e) q[e] = f2bf(v[i * 4 + e] * inv);
    *(us4*)(row + i * 256 + lane * 4) = q;
  }
  if (lane < 16) {
    us4 q;
#pragma unroll
    for (int e = 0; e < 4; ++e) q[e] = 0;
    if (lane == 0) q[0] = f2bf(e1024 * inv);
    *(us4*)(row + 1024 + lane * 4) = q;
  }
}

// ---------------------------------------------------------------------------
// reduce3: out = p0+p1+p2+p3 + (spatial ? xres + bdq : bd).
// ---------------------------------------------------------------------------
__global__ __launch_bounds__(256) void reduce3(const float* __restrict__ part,
                                               const float* __restrict__ xres,
                                               const float* __restrict__ bd,
                                               const float* __restrict__ bdq,
                                               float* __restrict__ out) {
  int t = blockIdx.x * 256 + threadIdx.x;    // < 524800
  long i = (long)t * 4;
  const long STR = 4100ll * 512;
  float4 a0 = *(const float4*)(part + i);
  float4 a1 = *(const float4*)(part + i + STR);
  float4 a2 = *(const float4*)(part + i + 2 * STR);
  float4 a3 = *(const float4*)(part + i + 3 * STR);
  int row = (int)(i >> 9);                   // 0..4099 = b*1025 + l
  int l = row % 1025;
  int ch = (int)(i & 511);
  float4 r;
  r.x = a0.x + a1.x + a2.x + a3.x;
  r.y = a0.y + a1.y + a2.y + a3.y;
  r.z = a0.z + a1.z + a2.z + a3.z;
  r.w = a0.w + a1.w + a2.w + a3.w;
  if (l > 0) {
    float4 xr = *(const float4*)(xres + i);
    float4 bb = *(const float4*)(bdq + ch);
    r.x += xr.x + bb.x; r.y += xr.y + bb.y;
    r.z += xr.z + bb.z; r.w += xr.w + bb.w;
  } else {
    float4 bb = *(const float4*)(bd + ch);
    r.x += bb.x; r.y += bb.y; r.z += bb.z; r.w += bb.w;
  }
  *(float4*)(out + i) = r;
}

// ---------------------------------------------------------------------------
// GEMM-BT: C[m][n] = sum_k A[m][k]*B[n][k], bf16, 128x128 tile, BK=64,
// staging XOR swizzle. Token order: cls at 1024 in PQ/PK/S/PVt.
// Modes:
//  0 PROJ : A=xb spatial rows (M=4096), B=Wc q|k sections, N=8192.
//           Sections (nt>>5): 0 PQ(+emb), 1 PK. Bias: bc.
//  2 PVT  : A=xb spatial, B=Wc v-section -> PVt, transposed epilogue. 1024 blk.
//  3 S    : 1D XCD head-grouped; interior 8x8 tiles only
//  4 O    : 1D XCD head-grouped; S*PVt^T -> stacked (NO residual), l=perm(q)
//  5 FIN  : A=stk, B=Wd, split-K x4 -> f32 partials
//  6 FOLD : Wc = Wp·W per head (B k-slow: rotated-source staging + strided
//           ds_read_u16 B-frags).
//  7 FOLDQ: Wdq[o][i] = sum_q Wd[o][q]·Wq[q][i], KLEN=4096, 16 blocks,
//           same rotated-B path as mode 6.
//  8 XRES : xres = x·Wdq^T -> f32 (row-remapped scalar epilogue). 128 blocks.
// ---------------------------------------------------------------------------
struct GP {
  const u16* A; const u16* A2; const u16* B; const u16* B2;
  const float* c0; const float* c1; const float* c2;
  const float* emb; const u16* resid;
  u16* o0; u16* o1; u16* o2;
  u16* p0; u16* p1; u16* p2;
  float* of; int bz0;
};

template <int MODE>
__global__ __launch_bounds__(256) void gemm_bt(GP g) {
  constexpr int KLEN = (MODE == 5) ? 1024 : ((MODE == 4) ? 1088 : ((MODE == 7) ? 4096 : 512));
  constexpr int KITER = KLEN / 64;
  __shared__ u16 smem[16384];          // As | Bs staging; epilogue tile reuse
  u16* As = smem;
  u16* Bs = smem + 8192;
  const int tid = threadIdx.x;
  const int lane = tid & 63;
  const int wv = tid >> 6;
  const int wr = wv >> 1, wc = wv & 1;
  const int ccol = lane & 15;
  const int rgrp = lane >> 4;

  // Block -> (mt, nt, bz). XCD grouping (flat&7) for modes 2/3/4.
  int mt, nt, bz, mh = 0;
  if constexpr (MODE == 3 || MODE == 4) {
    constexpr int PER = (MODE == 3) ? 64 : 36;   // mode3: interior 8x8 only
    constexpr int NTW = (MODE == 3) ? 8 : 4;
    int flat = blockIdx.x;
    int xcd = flat & 7, s = flat >> 3;
    bz = xcd + 8 * (s / PER);
    int tile = s % PER;
    mt = tile / NTW;
    nt = tile % NTW;
  } else if constexpr (MODE == 2) {
    int flat = blockIdx.x;               // 1024 blocks
    int xcd = flat & 7, s = flat >> 3;   // s: 0..127
    bz = 0;
    mt = xcd * 4 + (s >> 5);             // 0..31
    nt = s & 31;                         // 0..31
  } else if constexpr (MODE == 6) {
    int flat = blockIdx.x;               // 384 blocks
    mh = flat >> 4;                      // mat*8 + head, 0..23
    int tile = flat & 15;
    mt = tile >> 2; nt = tile & 3; bz = 0;
  } else if constexpr (MODE == 7 || MODE == 8) {
    mt = blockIdx.x >> 2; nt = blockIdx.x & 3; bz = 0;   // 16 / 128 blocks
  } else {
    mt = blockIdx.y; nt = blockIdx.x; bz = blockIdx.z;
  }
  const int gbz = g.bz0 + bz;

  const u16* Ap = g.A;
  const u16* Bp = g.B;

  int a_row[4], b_row[4], kx[4];
#pragma unroll
  for (int c = 0; c < 4; ++c) {
    int idx = c * 256 + tid;
    int row = idx >> 3;                       // 0..127
    kx[c] = ((idx & 7) ^ (row & 7)) * 8;      // swizzled k-chunk offset (elems)
    {
      int r = mt * 128 + row;
      int off;
      if constexpr (MODE == 0 || MODE == 2 || MODE == 8) { off = ((r >> 10) * 1025 + 1 + (r & 1023)) * 512; }
      else if constexpr (MODE == 3) { off = gbz * (1025 * 512) + r * 512; }
      else if constexpr (MODE == 4) { r = r < 1024 ? r : 1024; off = bz * (1025 * 1088) + r * 1088; }
      else if constexpr (MODE == 6) { off = (mh >> 3) * 262144 + r * 512; }
      else if constexpr (MODE == 7) { off = r * 4096; }
      else { r = r < 4099 ? r : 4099; off = r * 4096; }       // MODE 5
      a_row[c] = off;
    }
    {
      int off;
      if constexpr (MODE == 6 || MODE == 7) {
        int rb = idx >> 4, s2 = idx & 15;           // [64 c-rows][16 chunks]
        int cg = (s2 - ((rb >> 3) << 1)) & 15;      // inverse 16-elem rotation
        off = ((MODE == 6) ? mh * 262144 : 0) + rb * 512 + nt * 128 + cg * 8;
      } else {
        int r = nt * 128 + row;
        if constexpr (MODE == 3) { off = gbz * (1025 * 512) + r * 512; }
        else if constexpr (MODE == 4) { off = gbz * (512 * 1088) + r * 1088; }
        else if constexpr (MODE == 5) { off = r * 4096; }
        else { off = r * 512; }                     // MODE 0 / 2 / 8
      }
      b_row[c] = off;
    }
  }

  // Accumulators: modes 0/2 initialize with the per-column bias.
  floatx4 acc[4][4];
  {
    float binit[4] = {0.f, 0.f, 0.f, 0.f};
    if constexpr (MODE == 0) {
      int sec = nt >> 5;                           // 0 or 1
      const float* bs = g.c0 + sec * 4096;
#pragma unroll
      for (int j = 0; j < 4; ++j) binit[j] = bs[(nt & 31) * 128 + wc * 64 + j * 16 + ccol];
    }
    if constexpr (MODE == 2) {
#pragma unroll
      for (int j = 0; j < 4; ++j) binit[j] = g.c0[nt * 128 + wc * 64 + j * 16 + ccol];
    }
#pragma unroll
    for (int i = 0; i < 4; ++i)
#pragma unroll
      for (int j = 0; j < 4; ++j)
#pragma unroll
        for (int rr = 0; rr < 4; ++rr) acc[i][j][rr] = binit[j];
  }

  const int kbase = (MODE == 5) ? bz * 1024 : 0;
  const int l15 = lane & 15;
  const int lq = lane >> 4;
  const int l7 = lane & 7;

  for (int kt = 0; kt < KITER; ++kt) {
    const int k0 = kbase + kt * 64;
#pragma unroll
    for (int c = 0; c < 4; ++c)
      gld_lds16(Ap + a_row[c] + k0 + kx[c], (char*)As + (c * 256 + wv * 64) * 16);
#pragma unroll
    for (int c = 0; c < 4; ++c) {
      if constexpr (MODE == 6 || MODE == 7)
        gld_lds16(Bp + b_row[c] + k0 * 512, (char*)Bs + (c * 256 + wv * 64) * 16);
      else
        gld_lds16(Bp + b_row[c] + k0 + kx[c], (char*)Bs + (c * 256 + wv * 64) * 16);
    }
    __syncthreads();
#pragma unroll
    for (int ks = 0; ks < 2; ++ks) {
      const int ch = ((ks * 4 + lq) ^ l7) * 8;
      short8 af[4], bfr[4];
#pragma unroll
      for (int i = 0; i < 4; ++i)
        af[i] = *(const short8*)(As + (wr * 64 + i * 16 + l15) * 64 + ch);
      if constexpr (MODE == 6 || MODE == 7) {
        // B' is [k=64][i=128] with 16-elem rotation per k-octet:
        // elem(k,i) at k*128 + ((i + 16*(k>>3)) & 127).
#pragma unroll
        for (int j = 0; j < 4; ++j) {
          int ro = ((wc * 64 + j * 16 + l15) + ((ks * 4 + lq) << 4)) & 127;
          const u16* bp2 = Bs + (ks * 32 + lq * 8) * 128 + ro;
          short8 tv;
#pragma unroll
          for (int e = 0; e < 8; ++e) tv[e] = (short)bp2[e * 128];
          bfr[j] = tv;
        }
      } else {
#pragma unroll
        for (int j = 0; j < 4; ++j)
          bfr[j] = *(const short8*)(Bs + (wc * 64 + j * 16 + l15) * 64 + ch);
      }
#pragma unroll
      for (int i = 0; i < 4; ++i)
#pragma unroll
        for (int j = 0; j < 4; ++j)
          acc[i][j] = __builtin_amdgcn_mfma_f32_16x16x32_bf16(af[i], bfr[j], acc[i][j], 0, 0, 0);
    }
    __syncthreads();
  }

  // ---- Epilogue ---- (C/D frag: col = lane&15, row = (lane>>4)*4 + reg)
  if constexpr (MODE == 2) {
    // PVt: LDS-transposed epilogue [ch_local][sp_local], vector store
    // along sp (spatial at offset 0 in permuted PVt).
#pragma unroll
    for (int i = 0; i < 4; ++i)
#pragma unroll
      for (int j = 0; j < 4; ++j)
#pragma unroll
        for (int rr = 0; rr < 4; ++rr) {
          int lr2 = wc * 64 + j * 16 + ccol;            // ch-local
          int lc2 = wr * 64 + i * 16 + rgrp * 4 + rr;   // sp-local
          smem[lr2 * 128 + (lc2 ^ ((lr2 & 15) << 3))] = f2bf(acc[i][j][rr]);
        }
    __syncthreads();
    {
      int b = mt >> 3, sp0 = (mt & 7) * 128;
      int n = nt >> 2, ch0 = (nt & 3) * 128;
      long bn = b * 8 + n;
#pragma unroll
      for (int q = 0; q < 8; ++q) {
        int cid = q * 256 + tid;
        int r = cid >> 4;                 // ch-local 0..127
        int c = cid & 15;                 // sp chunk
        int pc = c ^ (r & 15);
        short8 val = *(const short8*)(smem + r * 128 + pc * 8);
        *(short8*)(g.o0 + (bn * 512 + ch0 + r) * 1088 + sp0 + c * 8) = val;
      }
    }
  } else if constexpr (MODE == 0 || MODE == 3 || MODE == 4 || MODE == 6 || MODE == 7) {
#pragma unroll
    for (int i = 0; i < 4; ++i)
#pragma unroll
      for (int j = 0; j < 4; ++j)
#pragma unroll
        for (int rr = 0; rr < 4; ++rr) {
          int lr = wr * 64 + i * 16 + rgrp * 4 + rr;
          int lc = wc * 64 + j * 16 + ccol;
          float v = acc[i][j][rr];
          if constexpr (MODE == 3) v *= 0.04419417382415922f;
          smem[lr * 128 + (lc ^ (rgrp << 4))] = f2bf(v);
        }
    __syncthreads();
#pragma unroll
    for (int q = 0; q < 8; ++q) {
      int cid = q * 256 + tid;
      int r = cid >> 4;                 // 0..127
      int c = cid & 15;                 // chunk
      int pc = c ^ ((((unsigned)r >> 2) & 3) << 1);
      short8 val = *(const short8*)(smem + r * 128 + pc * 8);
      int grow = mt * 128 + r;
      if constexpr (MODE == 0) {
        const int sec = nt >> 5;
        int b = grow >> 10, sp = grow & 1023;   // grow in 0..4095
        int gcol = (nt & 31) * 128 + c * 8;     // 0..4095 (n, ch)
        int n = gcol >> 9, ch2 = gcol & 511;
        long bn = b * 8 + n;
        if (sec == 0) {
          const float* ep = g.emb + sp * 512 + ch2;
          float4 e0 = *(const float4*)ep;
          float4 e1 = *(const float4*)(ep + 4);
          float ee[8] = {e0.x, e0.y, e0.z, e0.w, e1.x, e1.y, e1.z, e1.w};
          short8 outv;
#pragma unroll
          for (int e = 0; e < 8; ++e) outv[e] = (short)f2bf(bf2f((u16)val[e]) + ee[e]);
          *(short8*)(g.o0 + (bn * 1025 + sp) * 512 + ch2) = outv;        // PQ sp
        } else {
          *(short8*)(g.o1 + (bn * 1025 + sp) * 512 + ch2) = val;         // PK sp
        }
      } else if constexpr (MODE == 3) {
        // interior only: grow < 1024, gcol < 1024 guaranteed
        *(short8*)(g.o0 + ((long)bz * 1025 + grow) * 1088 + nt * 128 + c * 8) = val;
      } else if constexpr (MODE == 6 || MODE == 7) {
        *(short8*)(g.o0 + ((long)(mh * 512) + grow) * 512 + nt * 128 + c * 8) = val;
      } else {  // MODE 4 (no residual)
        if (grow <= 1024) {
          int gcol0 = nt * 128 + c * 8;          // 0..511
          int l = (grow == 1024) ? 0 : grow + 1; // permuted q -> original l
          int b = gbz >> 3, n = gbz & 7;
          *(short8*)(g.o0 + (((long)b * 1025 + l) * 8 + n) * 512 + gcol0) = val;
        }
      }
    }
  } else if constexpr (MODE == 8) {
    // xres: scalar f32 epilogue, spatial-row remap (cls rows never written).
#pragma unroll
    for (int i = 0; i < 4; ++i) {
#pragma unroll
      for (int j = 0; j < 4; ++j) {
        const int gcol = nt * 128 + wc * 64 + j * 16 + ccol;
#pragma unroll
        for (int rr = 0; rr < 4; ++rr) {
          const int grow = mt * 128 + wr * 64 + i * 16 + rgrp * 4 + rr;  // 0..4095
          const int orow = (grow >> 10) * 1025 + 1 + (grow & 1023);
          g.of[(long)orow * 512 + gcol] = acc[i][j][rr];
        }
      }
    }
  } else {
    // Scalar epilogue for mode 5 (f32 partials).
#pragma unroll
    for (int i = 0; i < 4; ++i) {
#pragma unroll
      for (int j = 0; j < 4; ++j) {
        const int gcol = nt * 128 + wc * 64 + j * 16 + ccol;
#pragma unroll
        for (int rr = 0; rr < 4; ++rr) {
          const int grow = mt * 128 + wr * 64 + i * 16 + rgrp * 4 + rr;
          if (grow < 4100)
            g.of[((long)bz * 4100 + grow) * 512 + gcol] = acc[i][j][rr];
        }
      }
    }
  }
}

// ---------------------------------------------------------------------------
extern "C" void kernel_launch(void* const* d_in, const int* in_sizes, int n_in,
                              void* d_out, int out_size, void* d_ws, size_t ws_size,
                              hipStream_t stream) {
  const float* x   = (const float*)d_in[0];
  const float* Wq  = (const float*)d_in[1];
  const float* bq  = (const float*)d_in[2];
  const float* Wk  = (const float*)d_in[3];
  const float* bk  = (const float*)d_in[4];
  const float* Wv  = (const float*)d_in[5];
  const float* bv  = (const float*)d_in[6];
  const float* Wpq = (const float*)d_in[7];
  const float* bpq = (const float*)d_in[8];
  const float* Wpk = (const float*)d_in[9];
  const float* bpk = (const float*)d_in[10];
  const float* Wpv = (const float*)d_in[11];
  const float* bpv = (const float*)d_in[12];
  const float* Wd  = (const float*)d_in[13];
  const float* bd  = (const float*)d_in[14];
  float* out = (float*)d_out;

  char* ws = (char*)d_ws;
  size_t off = 0;
  auto alloc = [&](size_t bytes) {
    char* p = ws + off;
    off += (bytes + 255) & ~(size_t)255;
    return p;
  };
  // Persistent through attention:
  u16* Wpqb = (u16*)alloc(512ull * 512 * 2);          // contiguous triple
  u16* Wpkb = (u16*)alloc(512ull * 512 * 2);
  u16* Wpvb = (u16*)alloc(512ull * 512 * 2);
  u16* Wdb  = (u16*)alloc(4096ull * 512 * 2);
  u16* PQ   = (u16*)alloc(32ull * 1025 * 512 * 2);   // later: 4x f32 partials
  u16* PK   = (u16*)alloc(32ull * 1025 * 512 * 2);   // later: stk (nchunk=1)
  u16* PVt  = (u16*)alloc(32ull * 512 * 1088 * 2);
  float* xres = (float*)alloc(4100ull * 512 * 4);     // Q-residual partial
  float* bdq  = (float*)alloc(512ull * 4);            // bd + Wd·bq
  // Dead-by-attention group (S aliases from here):
  size_t s_off = off;
  u16* xb   = (u16*)alloc(4100ull * 512 * 2);
  u16* Wqb  = (u16*)alloc(4096ull * 512 * 2);   // Wqb|Wkb|Wvb contiguous
  u16* Wkb  = (u16*)alloc(4096ull * 512 * 2);
  u16* Wvb  = (u16*)alloc(4096ull * 512 * 2);
  u16* Wc   = (u16*)alloc(3ull * 4096 * 512 * 2);     // folded Wp·W
  float* bc = (float*)alloc(3ull * 4096 * 4);         // folded biases
  float* embp = (float*)alloc(1024ull * 512 * 4);
  u16* Wdq  = (u16*)alloc(512ull * 512 * 2);          // folded Wd·Wq
  size_t fixed_need = off;
  u16* S = (u16*)(ws + s_off);
  float* part = (float*)PQ;   // PQ dead before partials written (4x fits exactly)
  (void)in_sizes; (void)n_in; (void)out_size; (void)Wkb; (void)Wvb;
  (void)Wpkb; (void)Wpvb;

  const size_t sbytes = 1025ull * 1088 * 2;
  size_t need1 = s_off + 32ull * sbytes;
  size_t need2 = s_off + 16ull * sbytes;
  size_t stk4_off = s_off + ((8ull * sbytes + 255) & ~(size_t)255);
  size_t need4 = stk4_off + 4100ull * 4096 * 2;
  int nchunk;
  u16* stk;
  if (ws_size >= need1)      { nchunk = 1; stk = PK; }   // PK dead after mode 3
  else if (ws_size >= need2 && ws_size >= fixed_need) { nchunk = 2; stk = PK; }
  else if (ws_size >= need4 && ws_size >= fixed_need) {
    nchunk = 4; stk = (u16*)(ws + stk4_off);
  } else return;  // clean fail instead of GPU fault
  if (nchunk == 2) {
    size_t stk2_off = s_off + ((16ull * sbytes + 255) & ~(size_t)255);
    if (ws_size >= stk2_off + 4100ull * 4096 * 2) stk = (u16*)(ws + stk2_off);
    else {
      nchunk = 4;
      if (ws_size >= need4) stk = (u16*)(ws + stk4_off);
      else return;
    }
  }
  int hpc = 32 / nchunk;

  // 1) dtype conversions + pos-embed (one launch)
  CvtArgs ca;
  ca.src[0] = x;   ca.dst[0] = xb;   ca.n4[0] = 4100 * 512 / 4;
  ca.src[1] = Wq;  ca.dst[1] = Wqb;  ca.n4[1] = 4096 * 512 / 4;
  ca.src[2] = Wk;  ca.dst[2] = Wkb;  ca.n4[2] = 4096 * 512 / 4;
  ca.src[3] = Wv;  ca.dst[3] = Wvb;  ca.n4[3] = 4096 * 512 / 4;
  ca.src[4] = Wpq; ca.dst[4] = Wpqb; ca.n4[4] = 512 * 512 / 4;
  ca.src[5] = Wpk; ca.dst[5] = Wpkb; ca.n4[5] = 512 * 512 / 4;
  ca.src[6] = Wpv; ca.dst[6] = Wpvb; ca.n4[6] = 512 * 512 / 4;
  ca.src[7] = Wd;  ca.dst[7] = Wdb;  ca.n4[7] = 512 * 4096 / 4;
  int total4 = 0;
  for (int s = 0; s < 8; ++s) total4 += ca.n4[s];
  int grid1 = (total4 + 1024 * 512 / 4 + 255) / 256;
  cvt_all<<<grid1, 256, 0, stream>>>(ca, total4, embp);

  // 2a) weight folds: Wc = Wp·W (per head) and Wdq = Wd·Wq
  {
    GP g = {};
    g.A = Wpqb; g.B = Wqb; g.o0 = Wc;
    gemm_bt<6><<<dim3(384, 1, 1), 256, 0, stream>>>(g);
  }
  {
    GP g = {};
    g.A = Wdb; g.B = Wqb; g.o0 = Wdq;
    gemm_bt<7><<<dim3(16, 1, 1), 256, 0, stream>>>(g);
  }
  // 2b) cls rows of PQ/PK/PVt + folded biases bc, bdq (wave-parallel)
  {
    CF cf;
    cf.W = Wqb; cf.Wp = Wpqb; cf.Wdbp = Wdb; cf.xb = xb;
    cf.bq = bq; cf.bk = bk; cf.bv = bv;
    cf.bpq = bpq; cf.bpk = bpk; cf.bpv = bpv; cf.bd = bd;
    cf.PQ = PQ; cf.PK = PK; cf.PVt = PVt; cf.bc = bc; cf.bdq = bdq;
    cls_fold<<<6272, 256, 0, stream>>>(cf);
  }

  // 3) fused projection+pool: x -> PQ(+emb) | PK (spatial rows)
  {
    GP g = {};
    g.A = xb; g.B = Wc;
    g.c0 = bc; g.emb = embp;
    g.o0 = PQ; g.o1 = PK;
    gemm_bt<0><<<dim3(64, 32, 1), 256, 0, stream>>>(g);
  }
  // 3b) PVt: x · Wc_v^T via transposed epilogue
  {
    GP g = {};
    g.A = xb; g.B = Wc + 8192 * 512; g.c0 = bc + 8192; g.o0 = PVt;
    gemm_bt<2><<<dim3(1024, 1, 1), 256, 0, stream>>>(g);
  }
  // 3c) xres = x · Wdq^T (f32, consumed by reduce3)
  {
    GP g = {};
    g.A = xb; g.B = Wdq; g.of = xres;
    gemm_bt<8><<<dim3(128, 1, 1), 256, 0, stream>>>(g);
  }
  // xb, Wq/k/v, Wc, bc, embp, Wdq now dead -> S aliases them.

  // 4) attention: interior S tiles + S edge -> softmax -> O (no residual).
  for (int c = 0; c < nchunk; ++c) {
    GP g3 = {}; g3.A = PQ; g3.B = PK; g3.o0 = S; g3.bz0 = c * hpc;
    gemm_bt<3><<<dim3(64 * hpc, 1, 1), 256, 0, stream>>>(g3);
    s_edge<<<hpc * 8, 256, 0, stream>>>(
        PQ + (long)c * hpc * 1025 * 512, PK + (long)c * hpc * 1025 * 512, S, hpc);
    softmax_rows<<<257 * hpc, 256, 0, stream>>>(S);
    GP g4 = {}; g4.A = S; g4.B = PVt; g4.o0 = stk; g4.bz0 = c * hpc;
    gemm_bt<4><<<dim3(36 * hpc, 1, 1), 256, 0, stream>>>(g4);
  }
  // PQ dead -> 4x f32 partials alias it.

  // 5) final projection, split-K x4 -> partials, then reduce (+bias/resid)
  {
    GP g = {}; g.A = stk; g.B = Wdb; g.of = part;
    gemm_bt<5><<<dim3(4, 33, 4), 256, 0, stream>>>(g);
  }
  reduce3<<<(4100 * 512 / 4 + 255) / 256, 256, 0, stream>>>(part, xres, bd, bdq, out);
}

// Round 15
// 443.515 us; speedup vs baseline: 1.1399x; 1.1399x over previous
//
#include <hip/hip_runtime.h>

// ---------------------------------------------------------------------------
// MultiHeadPooledSelfAttention on gfx950.
// R21 = R20 with mode-7 fixed + mode-5 unbundled:
//  * mode-7 (Wdq=Wd·Wq fold) was 77 us at 16 blocks (latency-bound, 0.7% occ,
//    MfmaUtil 1%). Now split-K x8: 128 blocks, KITER=8, f32 partials into the
//    xres buffer (dead until mode-8), summed by wdq_reduce -> bf16 Wdq.
//  * mode-5 reverted to split-K x2 (R19-measured config; x4 was bundled
//    unmeasured into the R20 regression).
// Keeps: Q-residual fold ((Q+attn)Wd^T = attn Wd^T + x Wdq^T + bdq; Q never
// materialized; mode-0 N=8192 PQ|PK), Wc=Wp·W fold (mode-6), wave-parallel
// cls_fold, PVt mode-2, BK=64 staging XOR swizzle, bias via acc-init, XCD
// grouping, wave softmax, permuted token order (cls at 1024).
// ---------------------------------------------------------------------------

typedef unsigned short u16;
typedef __attribute__((ext_vector_type(8))) short short8;   // 8 x bf16
typedef __attribute__((ext_vector_type(4))) float floatx4;
typedef __attribute__((ext_vector_type(4))) unsigned short us4;

__device__ __forceinline__ u16 f2bf(float f) {
  union { float f; unsigned u; } x; x.f = f;
  unsigned r = (x.u + 0x7fffu + ((x.u >> 16) & 1u)) >> 16;
  return (u16)r;
}
__device__ __forceinline__ float bf2f(u16 u) {
  union { unsigned u; float f; } x; x.u = ((unsigned)u) << 16;
  return x.f;
}

__device__ __forceinline__ void gld_lds16(const void* g, void* l) {
  __builtin_amdgcn_global_load_lds(
      (const __attribute__((address_space(1))) void*)g,
      (__attribute__((address_space(3))) void*)l, 16, 0, 0);
}

// ---------------------------------------------------------------------------
struct CvtArgs { const float* src[8]; u16* dst[8]; int n4[8]; };

__global__ __launch_bounds__(256) void cvt_all(CvtArgs a, int total4, float* __restrict__ e) {
  int t = blockIdx.x * 256 + threadIdx.x;
  if (t >= total4) {
    int et = (t - total4) * 4;                  // emb flat base, < 1024*512
    if (et >= 1024 * 512) return;
#pragma unroll
    for (int u = 0; u < 4; ++u) {
      int idx = et + u;
      int c = idx & 511, sp = idx >> 9;
      int y = sp >> 5, xg = sp & 31;
      int j = c & 127, seg = c >> 7;
      float omega = expf(-(float)j * (9.210340371976184f / 128.f));
      float arg = (float)((seg < 2) ? y : xg) * omega;
      e[idx] = (seg & 1) ? cosf(arg) : sinf(arg);
    }
    return;
  }
#pragma unroll
  for (int s = 0; s < 8; ++s) {
    if (t < a.n4[s]) {
      const float* sp = a.src[s] + (long)t * 4;
      u16* dp = a.dst[s] + (long)t * 4;
      float4 v = *(const float4*)sp;
      dp[0] = f2bf(v.x); dp[1] = f2bf(v.y); dp[2] = f2bf(v.z); dp[3] = f2bf(v.w);
      return;
    }
    t -= a.n4[s];
  }
}

// ---------------------------------------------------------------------------
// cls_fold (wave-parallel): one WAVE per dot.
//  wid < 12288 : cls rows Q/K/V_cls[b][o2] -> PQ/PK row 1024, PVt col 1024.
//  wid < 24576 : folded pool bias bc[t2] = Wp[o,:]·b[n*512..] + bp[o].
//  wid < 25088 : bdq[o] = bd[o] + Wd[o,:]·bq  (Q-residual bias fold, K=4096).
// ---------------------------------------------------------------------------
struct CF {
  const u16* W;      // Wqb|Wkb|Wvb contiguous
  const u16* Wp;     // Wpqb|Wpkb|Wpvb contiguous
  const u16* Wdbp;   // Wdb (512 x 4096)
  const u16* xb;
  const float *bq, *bk, *bv, *bpq, *bpk, *bpv, *bd;
  u16 *PQ, *PK, *PVt;
  float* bc;
  float* bdq;
};

__global__ __launch_bounds__(256) void cls_fold(CF a) {
  int wid = blockIdx.x * 4 + (threadIdx.x >> 6);   // 0..25087
  int lane = threadIdx.x & 63;
  if (wid < 12288) {
    int mat = wid >> 12, o2 = wid & 4095, n = o2 >> 9, ch = o2 & 511;
    short8 wv = *(const short8*)(a.W + (long)wid * 512 + lane * 8);
    float wf[8];
#pragma unroll
    for (int e = 0; e < 8; ++e) wf[e] = bf2f((u16)wv[e]);
    float ac[4] = {0.f, 0.f, 0.f, 0.f};
#pragma unroll
    for (int b = 0; b < 4; ++b) {
      short8 xv = *(const short8*)(a.xb + ((long)b * 1025) * 512 + lane * 8);
#pragma unroll
      for (int e = 0; e < 8; ++e) ac[b] += wf[e] * bf2f((u16)xv[e]);
    }
#pragma unroll
    for (int o = 32; o > 0; o >>= 1)
#pragma unroll
      for (int b = 0; b < 4; ++b) ac[b] += __shfl_xor(ac[b], o, 64);
    if (lane == 0) {
      const float* bsrc = (mat == 0) ? a.bq : (mat == 1) ? a.bk : a.bv;
      float bias = bsrc[o2];
#pragma unroll
      for (int b = 0; b < 4; ++b) {
        long bn = b * 8 + n;
        u16 v = f2bf(ac[b] + bias);
        if (mat == 0)      a.PQ[(bn * 1025 + 1024) * 512 + ch] = v;
        else if (mat == 1) a.PK[(bn * 1025 + 1024) * 512 + ch] = v;
        else               a.PVt[(bn * 512 + ch) * 1088 + 1024] = v;
      }
    }
  } else if (wid < 24576) {
    int t2 = wid - 12288;
    int mat = t2 >> 12, o2 = t2 & 4095, n = o2 >> 9, o = o2 & 511;
    const float* bsrc = (mat == 0) ? a.bq : (mat == 1) ? a.bk : a.bv;
    short8 wp = *(const short8*)(a.Wp + (long)mat * 262144 + o * 512 + lane * 8);
    const float* bb = bsrc + n * 512 + lane * 8;
    float4 b0 = *(const float4*)bb;
    float4 b1 = *(const float4*)(bb + 4);
    float bf8[8] = {b0.x, b0.y, b0.z, b0.w, b1.x, b1.y, b1.z, b1.w};
    float s = 0.f;
#pragma unroll
    for (int e = 0; e < 8; ++e) s += bf2f((u16)wp[e]) * bf8[e];
#pragma unroll
    for (int o1 = 32; o1 > 0; o1 >>= 1) s += __shfl_xor(s, o1, 64);
    if (lane == 0) {
      const float* bpp = (mat == 0) ? a.bpq : (mat == 1) ? a.bpk : a.bpv;
      a.bc[t2] = s + bpp[o];
    }
  } else {
    int o = wid - 24576;                 // 0..511
    float s = 0.f;
    for (int c8 = 0; c8 < 8; ++c8) {
      int base = c8 * 512 + lane * 8;
      short8 wv = *(const short8*)(a.Wdbp + (long)o * 4096 + base);
      float4 b0 = *(const float4*)(a.bq + base);
      float4 b1 = *(const float4*)(a.bq + base + 4);
      float bf8[8] = {b0.x, b0.y, b0.z, b0.w, b1.x, b1.y, b1.z, b1.w};
#pragma unroll
      for (int e = 0; e < 8; ++e) s += bf2f((u16)wv[e]) * bf8[e];
    }
#pragma unroll
    for (int o1 = 32; o1 > 0; o1 >>= 1) s += __shfl_xor(s, o1, 64);
    if (lane == 0) a.bdq[o] = a.bd[o] + s;
  }
}

// ---------------------------------------------------------------------------
// wdq_reduce: Wdq = bf16( sum of 8 f32 split-K partials ).
// ---------------------------------------------------------------------------
__global__ __launch_bounds__(256) void wdq_reduce(const float* __restrict__ p,
                                                  u16* __restrict__ Wdq) {
  int t = blockIdx.x * 256 + threadIdx.x;    // < 65536
  long i = (long)t * 4;
  float4 s = *(const float4*)(p + i);
#pragma unroll
  for (int k = 1; k < 8; ++k) {
    float4 v = *(const float4*)(p + (long)k * 262144 + i);
    s.x += v.x; s.y += v.y; s.z += v.z; s.w += v.w;
  }
  u16* d = Wdq + i;
  d[0] = f2bf(s.x); d[1] = f2bf(s.y); d[2] = f2bf(s.z); d[3] = f2bf(s.w);
}

// ---------------------------------------------------------------------------
// S edge (permuted order: cls = index 1024): S[1024][kv] kv<=1024 and
// S[q][1024] q<1024 -> 2049 dots of length 512 per head. One dot per thread.
// ---------------------------------------------------------------------------
__global__ __launch_bounds__(256) void s_edge(const u16* __restrict__ PQ,
                                              const u16* __restrict__ PK,
                                              u16* __restrict__ S, int nh) {
  int flat = blockIdx.x;                 // nh*8
  int head, seg;
  if (nh == 32) {
    int xcd = flat & 7, s = flat >> 3;   // s: 0..31
    head = xcd + 8 * (s >> 3);           // 0..31
    seg = s & 7;
  } else {
    head = flat >> 3;
    seg = flat & 7;
  }
  const u16* pq = PQ + (long)head * 1025 * 512;
  const u16* pk = PK + (long)head * 1025 * 512;
  u16* sh = S + (long)head * 1025 * 1088;
#pragma unroll
  for (int i = 0; i < 2; ++i) {
    int local = i * 256 + (int)threadIdx.x;
    if (local >= 257) continue;
    int e = seg * 257 + local;
    if (e >= 2049) continue;
    int q, kv;
    if (e < 1025) { q = 1024; kv = e; }
    else { q = e - 1025; kv = 1024; }
    const u16* a = pq + (long)q * 512;
    const u16* b = pk + (long)kv * 512;
    float acc = 0.f;
    for (int k8 = 0; k8 < 64; ++k8) {
      short8 av = *(const short8*)(a + k8 * 8);
      short8 bv = *(const short8*)(b + k8 * 8);
#pragma unroll
      for (int u = 0; u < 8; ++u) acc += bf2f((u16)av[u]) * bf2f((u16)bv[u]);
    }
    sh[(long)q * 1088 + kv] = f2bf(acc * 0.04419417382415922f);
  }
}

// ---------------------------------------------------------------------------
// Softmax: one WAVE per row, 4 rows/block. XCD head-grouped.
// ---------------------------------------------------------------------------
__global__ __launch_bounds__(256) void softmax_rows(u16* __restrict__ S) {
  int flat = blockIdx.x;
  int xcd = flat & 7, s0 = flat >> 3;
  int zi = s0 / 257, blk = s0 - zi * 257;
  int head = xcd + 8 * zi;
  int wv = threadIdx.x >> 6, lane = threadIdx.x & 63;
  int row_i = blk * 4 + wv;
  if (row_i > 1024) return;
  u16* row = S + ((long)head * 1025 + row_i) * 1088;
  float v[16];
  float mx = -1e30f;
#pragma unroll
  for (int i = 0; i < 4; ++i) {
    us4 p = *(const us4*)(row + i * 256 + lane * 4);
#pragma unroll
    for (int e = 0; e < 4; ++e) { v[i * 4 + e] = bf2f(p[e]); mx = fmaxf(mx, v[i * 4 + e]); }
  }
  float e1024 = (lane == 0) ? bf2f(row[1024]) : -1e30f;
  mx = fmaxf(mx, e1024);
  for (int o = 32; o > 0; o >>= 1) mx = fmaxf(mx, __shfl_xor(mx, o, 64));
  float s = 0.f;
#pragma unroll
  for (int i = 0; i < 16; ++i) { v[i] = __expf(v[i] - mx); s += v[i]; }
  e1024 = (lane == 0) ? __expf(e1024 - mx) : 0.f;
  s += e1024;
  for (int o = 32; o > 0; o >>= 1) s += __shfl_xor(s, o, 64);
  float inv = 1.0f / s;
#pragma unroll
  for (int i = 0; i < 4; ++i) {
    us4 q;
#pragma unroll
    for (int e = 0; e < 4; ++e) q[e] = f2bf(v[i * 4 + e] * inv);
    *(us4*)(row + i * 256 + lane * 4) = q;
  }
  if (lane < 16) {
    us4 q;
#pragma unroll
    for (int e = 0; e < 4; ++e) q[e] = 0;
    if (lane == 0) q[0] = f2bf(e1024 * inv);
    *(us4*)(row + 1024 + lane * 4) = q;
  }
}

// ---------------------------------------------------------------------------
// reduce3: out = p0+p1 + (spatial ? xres + bdq : bd).
// ---------------------------------------------------------------------------
__global__ __launch_bounds__(256) void reduce3(const float* __restrict__ part,
                                               const float* __restrict__ xres,
                                               const float* __restrict__ bd,
                                               const float* __restrict__ bdq,
                                               float* __restrict__ out) {
  int t = blockIdx.x * 256 + threadIdx.x;    // < 524800
  long i = (long)t * 4;
  const long STR = 4100ll * 512;
  float4 a0 = *(const float4*)(part + i);
  float4 a1 = *(const float4*)(part + i + STR);
  int row = (int)(i >> 9);                   // 0..4099 = b*1025 + l
  int l = row % 1025;
  int ch = (int)(i & 511);
  float4 r;
  r.x = a0.x + a1.x;
  r.y = a0.y + a1.y;
  r.z = a0.z + a1.z;
  r.w = a0.w + a1.w;
  if (l > 0) {
    float4 xr = *(const float4*)(xres + i);
    float4 bb = *(const float4*)(bdq + ch);
    r.x += xr.x + bb.x; r.y += xr.y + bb.y;
    r.z += xr.z + bb.z; r.w += xr.w + bb.w;
  } else {
    float4 bb = *(const float4*)(bd + ch);
    r.x += bb.x; r.y += bb.y; r.z += bb.z; r.w += bb.w;
  }
  *(float4*)(out + i) = r;
}

// ---------------------------------------------------------------------------
// GEMM-BT: C[m][n] = sum_k A[m][k]*B[n][k], bf16, 128x128 tile, BK=64,
// staging XOR swizzle. Token order: cls at 1024 in PQ/PK/S/PVt.
// Modes:
//  0 PROJ : A=xb spatial rows (M=4096), B=Wc q|k sections, N=8192.
//           Sections (nt>>5): 0 PQ(+emb), 1 PK. Bias: bc.
//  2 PVT  : A=xb spatial, B=Wc v-section -> PVt, transposed epilogue. 1024 blk.
//  3 S    : 1D XCD head-grouped; interior 8x8 tiles only
//  4 O    : 1D XCD head-grouped; S*PVt^T -> stacked (NO residual), l=perm(q)
//  5 FIN  : A=stk, B=Wd, split-K x2 -> f32 partials
//  6 FOLD : Wc = Wp·W per head (B k-slow: rotated-source staging + strided
//           ds_read_u16 B-frags).
//  7 FOLDQ: Wdq partials = Wd·Wq split-K x8, grid (16,1,8), f32 scalar
//           epilogue; same rotated-B path as mode 6. Summed by wdq_reduce.
//  8 XRES : xres = x·Wdq^T -> f32 (row-remapped scalar epilogue). 128 blocks.
// ---------------------------------------------------------------------------
struct GP {
  const u16* A; const u16* A2; const u16* B; const u16* B2;
  const float* c0; const float* c1; const float* c2;
  const float* emb; const u16* resid;
  u16* o0; u16* o1; u16* o2;
  u16* p0; u16* p1; u16* p2;
  float* of; int bz0;
};

template <int MODE>
__global__ __launch_bounds__(256) void gemm_bt(GP g) {
  constexpr int KLEN = (MODE == 5) ? 2048 : ((MODE == 4) ? 1088 : 512);
  constexpr int KITER = KLEN / 64;
  __shared__ u16 smem[16384];          // As | Bs staging; epilogue tile reuse
  u16* As = smem;
  u16* Bs = smem + 8192;
  const int tid = threadIdx.x;
  const int lane = tid & 63;
  const int wv = tid >> 6;
  const int wr = wv >> 1, wc = wv & 1;
  const int ccol = lane & 15;
  const int rgrp = lane >> 4;

  // Block -> (mt, nt, bz). XCD grouping (flat&7) for modes 2/3/4.
  int mt, nt, bz, mh = 0;
  if constexpr (MODE == 3 || MODE == 4) {
    constexpr int PER = (MODE == 3) ? 64 : 36;   // mode3: interior 8x8 only
    constexpr int NTW = (MODE == 3) ? 8 : 4;
    int flat = blockIdx.x;
    int xcd = flat & 7, s = flat >> 3;
    bz = xcd + 8 * (s / PER);
    int tile = s % PER;
    mt = tile / NTW;
    nt = tile % NTW;
  } else if constexpr (MODE == 2) {
    int flat = blockIdx.x;               // 1024 blocks
    int xcd = flat & 7, s = flat >> 3;   // s: 0..127
    bz = 0;
    mt = xcd * 4 + (s >> 5);             // 0..31
    nt = s & 31;                         // 0..31
  } else if constexpr (MODE == 6) {
    int flat = blockIdx.x;               // 384 blocks
    mh = flat >> 4;                      // mat*8 + head, 0..23
    int tile = flat & 15;
    mt = tile >> 2; nt = tile & 3; bz = 0;
  } else if constexpr (MODE == 7) {
    mt = blockIdx.x >> 2; nt = blockIdx.x & 3; bz = blockIdx.z;   // (16,1,8)
  } else if constexpr (MODE == 8) {
    mt = blockIdx.x >> 2; nt = blockIdx.x & 3; bz = 0;   // 128 blocks
  } else {
    mt = blockIdx.y; nt = blockIdx.x; bz = blockIdx.z;
  }
  const int gbz = g.bz0 + bz;

  const u16* Ap = g.A;
  const u16* Bp = g.B;

  int a_row[4], b_row[4], kx[4];
#pragma unroll
  for (int c = 0; c < 4; ++c) {
    int idx = c * 256 + tid;
    int row = idx >> 3;                       // 0..127
    kx[c] = ((idx & 7) ^ (row & 7)) * 8;      // swizzled k-chunk offset (elems)
    {
      int r = mt * 128 + row;
      int off;
      if constexpr (MODE == 0 || MODE == 2 || MODE == 8) { off = ((r >> 10) * 1025 + 1 + (r & 1023)) * 512; }
      else if constexpr (MODE == 3) { off = gbz * (1025 * 512) + r * 512; }
      else if constexpr (MODE == 4) { r = r < 1024 ? r : 1024; off = bz * (1025 * 1088) + r * 1088; }
      else if constexpr (MODE == 6) { off = (mh >> 3) * 262144 + r * 512; }
      else if constexpr (MODE == 7) { off = r * 4096; }
      else { r = r < 4099 ? r : 4099; off = r * 4096; }       // MODE 5
      a_row[c] = off;
    }
    {
      int off;
      if constexpr (MODE == 6 || MODE == 7) {
        int rb = idx >> 4, s2 = idx & 15;           // [64 c-rows][16 chunks]
        int cg = (s2 - ((rb >> 3) << 1)) & 15;      // inverse 16-elem rotation
        off = ((MODE == 6) ? mh * 262144 : 0) + rb * 512 + nt * 128 + cg * 8;
      } else {
        int r = nt * 128 + row;
        if constexpr (MODE == 3) { off = gbz * (1025 * 512) + r * 512; }
        else if constexpr (MODE == 4) { off = gbz * (512 * 1088) + r * 1088; }
        else if constexpr (MODE == 5) { off = r * 4096; }
        else { off = r * 512; }                     // MODE 0 / 2 / 8
      }
      b_row[c] = off;
    }
  }

  // Accumulators: modes 0/2 initialize with the per-column bias.
  floatx4 acc[4][4];
  {
    float binit[4] = {0.f, 0.f, 0.f, 0.f};
    if constexpr (MODE == 0) {
      int sec = nt >> 5;                           // 0 or 1
      const float* bs = g.c0 + sec * 4096;
#pragma unroll
      for (int j = 0; j < 4; ++j) binit[j] = bs[(nt & 31) * 128 + wc * 64 + j * 16 + ccol];
    }
    if constexpr (MODE == 2) {
#pragma unroll
      for (int j = 0; j < 4; ++j) binit[j] = g.c0[nt * 128 + wc * 64 + j * 16 + ccol];
    }
#pragma unroll
    for (int i = 0; i < 4; ++i)
#pragma unroll
      for (int j = 0; j < 4; ++j)
#pragma unroll
        for (int rr = 0; rr < 4; ++rr) acc[i][j][rr] = binit[j];
  }

  const int kbase = (MODE == 5) ? bz * 2048 : ((MODE == 7) ? bz * 512 : 0);
  const int l15 = lane & 15;
  const int lq = lane >> 4;
  const int l7 = lane & 7;

  for (int kt = 0; kt < KITER; ++kt) {
    const int k0 = kbase + kt * 64;
#pragma unroll
    for (int c = 0; c < 4; ++c)
      gld_lds16(Ap + a_row[c] + k0 + kx[c], (char*)As + (c * 256 + wv * 64) * 16);
#pragma unroll
    for (int c = 0; c < 4; ++c) {
      if constexpr (MODE == 6 || MODE == 7)
        gld_lds16(Bp + b_row[c] + k0 * 512, (char*)Bs + (c * 256 + wv * 64) * 16);
      else
        gld_lds16(Bp + b_row[c] + k0 + kx[c], (char*)Bs + (c * 256 + wv * 64) * 16);
    }
    __syncthreads();
#pragma unroll
    for (int ks = 0; ks < 2; ++ks) {
      const int ch = ((ks * 4 + lq) ^ l7) * 8;
      short8 af[4], bfr[4];
#pragma unroll
      for (int i = 0; i < 4; ++i)
        af[i] = *(const short8*)(As + (wr * 64 + i * 16 + l15) * 64 + ch);
      if constexpr (MODE == 6 || MODE == 7) {
        // B' is [k=64][i=128] with 16-elem rotation per k-octet:
        // elem(k,i) at k*128 + ((i + 16*(k>>3)) & 127).
#pragma unroll
        for (int j = 0; j < 4; ++j) {
          int ro = ((wc * 64 + j * 16 + l15) + ((ks * 4 + lq) << 4)) & 127;
          const u16* bp2 = Bs + (ks * 32 + lq * 8) * 128 + ro;
          short8 tv;
#pragma unroll
          for (int e = 0; e < 8; ++e) tv[e] = (short)bp2[e * 128];
          bfr[j] = tv;
        }
      } else {
#pragma unroll
        for (int j = 0; j < 4; ++j)
          bfr[j] = *(const short8*)(Bs + (wc * 64 + j * 16 + l15) * 64 + ch);
      }
#pragma unroll
      for (int i = 0; i < 4; ++i)
#pragma unroll
        for (int j = 0; j < 4; ++j)
          acc[i][j] = __builtin_amdgcn_mfma_f32_16x16x32_bf16(af[i], bfr[j], acc[i][j], 0, 0, 0);
    }
    __syncthreads();
  }

  // ---- Epilogue ---- (C/D frag: col = lane&15, row = (lane>>4)*4 + reg)
  if constexpr (MODE == 2) {
    // PVt: LDS-transposed epilogue [ch_local][sp_local], vector store
    // along sp (spatial at offset 0 in permuted PVt).
#pragma unroll
    for (int i = 0; i < 4; ++i)
#pragma unroll
      for (int j = 0; j < 4; ++j)
#pragma unroll
        for (int rr = 0; rr < 4; ++rr) {
          int lr2 = wc * 64 + j * 16 + ccol;            // ch-local
          int lc2 = wr * 64 + i * 16 + rgrp * 4 + rr;   // sp-local
          smem[lr2 * 128 + (lc2 ^ ((lr2 & 15) << 3))] = f2bf(acc[i][j][rr]);
        }
    __syncthreads();
    {
      int b = mt >> 3, sp0 = (mt & 7) * 128;
      int n = nt >> 2, ch0 = (nt & 3) * 128;
      long bn = b * 8 + n;
#pragma unroll
      for (int q = 0; q < 8; ++q) {
        int cid = q * 256 + tid;
        int r = cid >> 4;                 // ch-local 0..127
        int c = cid & 15;                 // sp chunk
        int pc = c ^ (r & 15);
        short8 val = *(const short8*)(smem + r * 128 + pc * 8);
        *(short8*)(g.o0 + (bn * 512 + ch0 + r) * 1088 + sp0 + c * 8) = val;
      }
    }
  } else if constexpr (MODE == 0 || MODE == 3 || MODE == 4 || MODE == 6) {
#pragma unroll
    for (int i = 0; i < 4; ++i)
#pragma unroll
      for (int j = 0; j < 4; ++j)
#pragma unroll
        for (int rr = 0; rr < 4; ++rr) {
          int lr = wr * 64 + i * 16 + rgrp * 4 + rr;
          int lc = wc * 64 + j * 16 + ccol;
          float v = acc[i][j][rr];
          if constexpr (MODE == 3) v *= 0.04419417382415922f;
          smem[lr * 128 + (lc ^ (rgrp << 4))] = f2bf(v);
        }
    __syncthreads();
#pragma unroll
    for (int q = 0; q < 8; ++q) {
      int cid = q * 256 + tid;
      int r = cid >> 4;                 // 0..127
      int c = cid & 15;                 // chunk
      int pc = c ^ ((((unsigned)r >> 2) & 3) << 1);
      short8 val = *(const short8*)(smem + r * 128 + pc * 8);
      int grow = mt * 128 + r;
      if constexpr (MODE == 0) {
        const int sec = nt >> 5;
        int b = grow >> 10, sp = grow & 1023;   // grow in 0..4095
        int gcol = (nt & 31) * 128 + c * 8;     // 0..4095 (n, ch)
        int n = gcol >> 9, ch2 = gcol & 511;
        long bn = b * 8 + n;
        if (sec == 0) {
          const float* ep = g.emb + sp * 512 + ch2;
          float4 e0 = *(const float4*)ep;
          float4 e1 = *(const float4*)(ep + 4);
          float ee[8] = {e0.x, e0.y, e0.z, e0.w, e1.x, e1.y, e1.z, e1.w};
          short8 outv;
#pragma unroll
          for (int e = 0; e < 8; ++e) outv[e] = (short)f2bf(bf2f((u16)val[e]) + ee[e]);
          *(short8*)(g.o0 + (bn * 1025 + sp) * 512 + ch2) = outv;        // PQ sp
        } else {
          *(short8*)(g.o1 + (bn * 1025 + sp) * 512 + ch2) = val;         // PK sp
        }
      } else if constexpr (MODE == 3) {
        // interior only: grow < 1024, gcol < 1024 guaranteed
        *(short8*)(g.o0 + ((long)bz * 1025 + grow) * 1088 + nt * 128 + c * 8) = val;
      } else if constexpr (MODE == 6) {
        *(short8*)(g.o0 + ((long)(mh * 512) + grow) * 512 + nt * 128 + c * 8) = val;
      } else {  // MODE 4 (no residual)
        if (grow <= 1024) {
          int gcol0 = nt * 128 + c * 8;          // 0..511
          int l = (grow == 1024) ? 0 : grow + 1; // permuted q -> original l
          int b = gbz >> 3, n = gbz & 7;
          *(short8*)(g.o0 + (((long)b * 1025 + l) * 8 + n) * 512 + gcol0) = val;
        }
      }
    }
  } else if constexpr (MODE == 8) {
    // xres: scalar f32 epilogue, spatial-row remap (cls rows never written).
#pragma unroll
    for (int i = 0; i < 4; ++i) {
#pragma unroll
      for (int j = 0; j < 4; ++j) {
        const int gcol = nt * 128 + wc * 64 + j * 16 + ccol;
#pragma unroll
        for (int rr = 0; rr < 4; ++rr) {
          const int grow = mt * 128 + wr * 64 + i * 16 + rgrp * 4 + rr;  // 0..4095
          const int orow = (grow >> 10) * 1025 + 1 + (grow & 1023);
          g.of[(long)orow * 512 + gcol] = acc[i][j][rr];
        }
      }
    }
  } else if constexpr (MODE == 7) {
    // Wdq split-K partial: f32 scalar epilogue, [bz][512][512].
#pragma unroll
    for (int i = 0; i < 4; ++i) {
#pragma unroll
      for (int j = 0; j < 4; ++j) {
        const int gcol = nt * 128 + wc * 64 + j * 16 + ccol;
#pragma unroll
        for (int rr = 0; rr < 4; ++rr) {
          const int grow = mt * 128 + wr * 64 + i * 16 + rgrp * 4 + rr;  // 0..511
          g.of[(long)bz * 262144 + (long)grow * 512 + gcol] = acc[i][j][rr];
        }
      }
    }
  } else {
    // Scalar epilogue for mode 5 (f32 partials).
#pragma unroll
    for (int i = 0; i < 4; ++i) {
#pragma unroll
      for (int j = 0; j < 4; ++j) {
        const int gcol = nt * 128 + wc * 64 + j * 16 + ccol;
#pragma unroll
        for (int rr = 0; rr < 4; ++rr) {
          const int grow = mt * 128 + wr * 64 + i * 16 + rgrp * 4 + rr;
          if (grow < 4100)
            g.of[((long)bz * 4100 + grow) * 512 + gcol] = acc[i][j][rr];
        }
      }
    }
  }
}

// ---------------------------------------------------------------------------
extern "C" void kernel_launch(void* const* d_in, const int* in_sizes, int n_in,
                              void* d_out, int out_size, void* d_ws, size_t ws_size,
                              hipStream_t stream) {
  const float* x   = (const float*)d_in[0];
  const float* Wq  = (const float*)d_in[1];
  const float* bq  = (const float*)d_in[2];
  const float* Wk  = (const float*)d_in[3];
  const float* bk  = (const float*)d_in[4];
  const float* Wv  = (const float*)d_in[5];
  const float* bv  = (const float*)d_in[6];
  const float* Wpq = (const float*)d_in[7];
  const float* bpq = (const float*)d_in[8];
  const float* Wpk = (const float*)d_in[9];
  const float* bpk = (const float*)d_in[10];
  const float* Wpv = (const float*)d_in[11];
  const float* bpv = (const float*)d_in[12];
  const float* Wd  = (const float*)d_in[13];
  const float* bd  = (const float*)d_in[14];
  float* out = (float*)d_out;

  char* ws = (char*)d_ws;
  size_t off = 0;
  auto alloc = [&](size_t bytes) {
    char* p = ws + off;
    off += (bytes + 255) & ~(size_t)255;
    return p;
  };
  // Persistent through attention:
  u16* Wpqb = (u16*)alloc(512ull * 512 * 2);          // contiguous triple
  u16* Wpkb = (u16*)alloc(512ull * 512 * 2);
  u16* Wpvb = (u16*)alloc(512ull * 512 * 2);
  u16* Wdb  = (u16*)alloc(4096ull * 512 * 2);
  u16* PQ   = (u16*)alloc(32ull * 1025 * 512 * 2);   // later: 2x f32 partials
  u16* PK   = (u16*)alloc(32ull * 1025 * 512 * 2);   // later: stk (nchunk=1)
  u16* PVt  = (u16*)alloc(32ull * 512 * 1088 * 2);
  float* xres = (float*)alloc(4100ull * 512 * 4);     // Wdq partials, then x·Wdq^T
  float* bdq  = (float*)alloc(512ull * 4);            // bd + Wd·bq
  // Dead-by-attention group (S aliases from here):
  size_t s_off = off;
  u16* xb   = (u16*)alloc(4100ull * 512 * 2);
  u16* Wqb  = (u16*)alloc(4096ull * 512 * 2);   // Wqb|Wkb|Wvb contiguous
  u16* Wkb  = (u16*)alloc(4096ull * 512 * 2);
  u16* Wvb  = (u16*)alloc(4096ull * 512 * 2);
  u16* Wc   = (u16*)alloc(3ull * 4096 * 512 * 2);     // folded Wp·W
  float* bc = (float*)alloc(3ull * 4096 * 4);         // folded biases
  float* embp = (float*)alloc(1024ull * 512 * 4);
  u16* Wdq  = (u16*)alloc(512ull * 512 * 2);          // folded Wd·Wq
  size_t fixed_need = off;
  u16* S = (u16*)(ws + s_off);
  float* part = (float*)PQ;   // PQ dead before partials written
  (void)in_sizes; (void)n_in; (void)out_size; (void)Wkb; (void)Wvb;
  (void)Wpkb; (void)Wpvb;

  const size_t sbytes = 1025ull * 1088 * 2;
  size_t need1 = s_off + 32ull * sbytes;
  size_t need2 = s_off + 16ull * sbytes;
  size_t stk4_off = s_off + ((8ull * sbytes + 255) & ~(size_t)255);
  size_t need4 = stk4_off + 4100ull * 4096 * 2;
  int nchunk;
  u16* stk;
  if (ws_size >= need1)      { nchunk = 1; stk = PK; }   // PK dead after mode 3
  else if (ws_size >= need2 && ws_size >= fixed_need) { nchunk = 2; stk = PK; }
  else if (ws_size >= need4 && ws_size >= fixed_need) {
    nchunk = 4; stk = (u16*)(ws + stk4_off);
  } else return;  // clean fail instead of GPU fault
  if (nchunk == 2) {
    size_t stk2_off = s_off + ((16ull * sbytes + 255) & ~(size_t)255);
    if (ws_size >= stk2_off + 4100ull * 4096 * 2) stk = (u16*)(ws + stk2_off);
    else {
      nchunk = 4;
      if (ws_size >= need4) stk = (u16*)(ws + stk4_off);
      else return;
    }
  }
  int hpc = 32 / nchunk;

  // 1) dtype conversions + pos-embed (one launch)
  CvtArgs ca;
  ca.src[0] = x;   ca.dst[0] = xb;   ca.n4[0] = 4100 * 512 / 4;
  ca.src[1] = Wq;  ca.dst[1] = Wqb;  ca.n4[1] = 4096 * 512 / 4;
  ca.src[2] = Wk;  ca.dst[2] = Wkb;  ca.n4[2] = 4096 * 512 / 4;
  ca.src[3] = Wv;  ca.dst[3] = Wvb;  ca.n4[3] = 4096 * 512 / 4;
  ca.src[4] = Wpq; ca.dst[4] = Wpqb; ca.n4[4] = 512 * 512 / 4;
  ca.src[5] = Wpk; ca.dst[5] = Wpkb; ca.n4[5] = 512 * 512 / 4;
  ca.src[6] = Wpv; ca.dst[6] = Wpvb; ca.n4[6] = 512 * 512 / 4;
  ca.src[7] = Wd;  ca.dst[7] = Wdb;  ca.n4[7] = 512 * 4096 / 4;
  int total4 = 0;
  for (int s = 0; s < 8; ++s) total4 += ca.n4[s];
  int grid1 = (total4 + 1024 * 512 / 4 + 255) / 256;
  cvt_all<<<grid1, 256, 0, stream>>>(ca, total4, embp);

  // 2a) weight folds: Wc = Wp·W (per head); Wdq = Wd·Wq (split-K x8 + reduce)
  {
    GP g = {};
    g.A = Wpqb; g.B = Wqb; g.o0 = Wc;
    gemm_bt<6><<<dim3(384, 1, 1), 256, 0, stream>>>(g);
  }
  {
    GP g = {};
    g.A = Wdb; g.B = Wqb; g.of = xres;   // 8x f32 partials (8 MB) in xres
    gemm_bt<7><<<dim3(16, 1, 8), 256, 0, stream>>>(g);
  }
  wdq_reduce<<<256, 256, 0, stream>>>(xres, Wdq);
  // 2b) cls rows of PQ/PK/PVt + folded biases bc, bdq (wave-parallel)
  {
    CF cf;
    cf.W = Wqb; cf.Wp = Wpqb; cf.Wdbp = Wdb; cf.xb = xb;
    cf.bq = bq; cf.bk = bk; cf.bv = bv;
    cf.bpq = bpq; cf.bpk = bpk; cf.bpv = bpv; cf.bd = bd;
    cf.PQ = PQ; cf.PK = PK; cf.PVt = PVt; cf.bc = bc; cf.bdq = bdq;
    cls_fold<<<6272, 256, 0, stream>>>(cf);
  }

  // 3) fused projection+pool: x -> PQ(+emb) | PK (spatial rows)
  {
    GP g = {};
    g.A = xb; g.B = Wc;
    g.c0 = bc; g.emb = embp;
    g.o0 = PQ; g.o1 = PK;
    gemm_bt<0><<<dim3(64, 32, 1), 256, 0, stream>>>(g);
  }
  // 3b) PVt: x · Wc_v^T via transposed epilogue
  {
    GP g = {};
    g.A = xb; g.B = Wc + 8192 * 512; g.c0 = bc + 8192; g.o0 = PVt;
    gemm_bt<2><<<dim3(1024, 1, 1), 256, 0, stream>>>(g);
  }
  // 3c) xres = x · Wdq^T (f32, overwrites the Wdq partials; consumed by reduce3)
  {
    GP g = {};
    g.A = xb; g.B = Wdq; g.of = xres;
    gemm_bt<8><<<dim3(128, 1, 1), 256, 0, stream>>>(g);
  }
  // xb, Wq/k/v, Wc, bc, embp, Wdq now dead -> S aliases them.

  // 4) attention: interior S tiles + S edge -> softmax -> O (no residual).
  for (int c = 0; c < nchunk; ++c) {
    GP g3 = {}; g3.A = PQ; g3.B = PK; g3.o0 = S; g3.bz0 = c * hpc;
    gemm_bt<3><<<dim3(64 * hpc, 1, 1), 256, 0, stream>>>(g3);
    s_edge<<<hpc * 8, 256, 0, stream>>>(
        PQ + (long)c * hpc * 1025 * 512, PK + (long)c * hpc * 1025 * 512, S, hpc);
    softmax_rows<<<257 * hpc, 256, 0, stream>>>(S);
    GP g4 = {}; g4.A = S; g4.B = PVt; g4.o0 = stk; g4.bz0 = c * hpc;
    gemm_bt<4><<<dim3(36 * hpc, 1, 1), 256, 0, stream>>>(g4);
  }
  // PQ dead -> 2x f32 partials alias it.

  // 5) final projection, split-K x2 -> partials, then reduce (+bias/resid)
  {
    GP g = {}; g.A = stk; g.B = Wdb; g.of = part;
    gemm_bt<5><<<dim3(4, 33, 2), 256, 0, stream>>>(g);
  }
  reduce3<<<(4100 * 512 / 4 + 255) / 256, 256, 0, stream>>>(part, xres, bd, bdq, out);
}

// Round 19
// 430.580 us; speedup vs baseline: 1.1742x; 1.0300x over previous
//
#include <hip/hip_runtime.h>

// ---------------------------------------------------------------------------
// MultiHeadPooledSelfAttention on gfx950.
// R22 = R19 (best measured, 430.2 us) + mode-5 split-K x2 -> x4.
//   Q-residual fold (R20/R21) reverted: measured net-negative (helpers ~19us
//   + 3 launches vs -22us mode-0 shrink; R21=443.5 vs R19=430.2).
//   Mode-5 had 264 blocks = 1.03/CU (m97 structure needs ~3/CU co-residency);
//   x4 -> 528 blocks = 2.06/CU. 4 f32 partials alias PQ exactly (33.6 MB).
// Keeps (R19): pooler fold Wc=Wp·W (mode-6), wave-parallel cls_fold, mode-0
// N=12288 (PQ|PK|Q), PVt mode-2 transposed epilogue, BK=64 staging XOR
// swizzle, bias via acc-init, XCD grouping, wave softmax, permuted token
// order (cls at index 1024), residual in mode-4.
// ---------------------------------------------------------------------------

typedef unsigned short u16;
typedef __attribute__((ext_vector_type(8))) short short8;   // 8 x bf16
typedef __attribute__((ext_vector_type(4))) float floatx4;
typedef __attribute__((ext_vector_type(4))) unsigned short us4;

__device__ __forceinline__ u16 f2bf(float f) {
  union { float f; unsigned u; } x; x.f = f;
  unsigned r = (x.u + 0x7fffu + ((x.u >> 16) & 1u)) >> 16;
  return (u16)r;
}
__device__ __forceinline__ float bf2f(u16 u) {
  union { unsigned u; float f; } x; x.u = ((unsigned)u) << 16;
  return x.f;
}

__device__ __forceinline__ void gld_lds16(const void* g, void* l) {
  __builtin_amdgcn_global_load_lds(
      (const __attribute__((address_space(1))) void*)g,
      (__attribute__((address_space(3))) void*)l, 16, 0, 0);
}

// ---------------------------------------------------------------------------
struct CvtArgs { const float* src[8]; u16* dst[8]; int n4[8]; };

__global__ __launch_bounds__(256) void cvt_all(CvtArgs a, int total4, float* __restrict__ e) {
  int t = blockIdx.x * 256 + threadIdx.x;
  if (t >= total4) {
    int et = (t - total4) * 4;                  // emb flat base, < 1024*512
    if (et >= 1024 * 512) return;
#pragma unroll
    for (int u = 0; u < 4; ++u) {
      int idx = et + u;
      int c = idx & 511, sp = idx >> 9;
      int y = sp >> 5, xg = sp & 31;
      int j = c & 127, seg = c >> 7;
      float omega = expf(-(float)j * (9.210340371976184f / 128.f));
      float arg = (float)((seg < 2) ? y : xg) * omega;
      e[idx] = (seg & 1) ? cosf(arg) : sinf(arg);
    }
    return;
  }
#pragma unroll
  for (int s = 0; s < 8; ++s) {
    if (t < a.n4[s]) {
      const float* sp = a.src[s] + (long)t * 4;
      u16* dp = a.dst[s] + (long)t * 4;
      float4 v = *(const float4*)sp;
      dp[0] = f2bf(v.x); dp[1] = f2bf(v.y); dp[2] = f2bf(v.z); dp[3] = f2bf(v.w);
      return;
    }
    t -= a.n4[s];
  }
}

// ---------------------------------------------------------------------------
// cls_fold (wave-parallel): one WAVE per dot.
//  wid < 12288: cls rows  Q/K/V_cls[b][o2] = x[b,0,:]·W[o2,:] + b[o2]
//               -> PQ/PK row 1024, PVt col 1024 (4 batches per wave).
//  else       : folded pool bias bc[t2] = Wp[o,:]·b[n*512..] + bp[o].
// Lane l loads elems l*8..l*8+7 (coalesced 1 KB per wave); shfl_xor reduce.
// Grid: 6144 blocks x 256 (4 waves/block, 24576 waves total).
// ---------------------------------------------------------------------------
struct CF {
  const u16* W;      // Wqb|Wkb|Wvb contiguous
  const u16* Wp;     // Wpqb|Wpkb|Wpvb contiguous
  const u16* xb;
  const float *bq, *bk, *bv, *bpq, *bpk, *bpv;
  u16 *PQ, *PK, *PVt;
  float* bc;
};

__global__ __launch_bounds__(256) void cls_fold(CF a) {
  int wid = blockIdx.x * 4 + (threadIdx.x >> 6);   // 0..24575
  int lane = threadIdx.x & 63;
  if (wid < 12288) {
    int mat = wid >> 12, o2 = wid & 4095, n = o2 >> 9, ch = o2 & 511;
    short8 wv = *(const short8*)(a.W + (long)wid * 512 + lane * 8);
    float wf[8];
#pragma unroll
    for (int e = 0; e < 8; ++e) wf[e] = bf2f((u16)wv[e]);
    float ac[4] = {0.f, 0.f, 0.f, 0.f};
#pragma unroll
    for (int b = 0; b < 4; ++b) {
      short8 xv = *(const short8*)(a.xb + ((long)b * 1025) * 512 + lane * 8);
#pragma unroll
      for (int e = 0; e < 8; ++e) ac[b] += wf[e] * bf2f((u16)xv[e]);
    }
#pragma unroll
    for (int o = 32; o > 0; o >>= 1)
#pragma unroll
      for (int b = 0; b < 4; ++b) ac[b] += __shfl_xor(ac[b], o, 64);
    if (lane == 0) {
      const float* bsrc = (mat == 0) ? a.bq : (mat == 1) ? a.bk : a.bv;
      float bias = bsrc[o2];
#pragma unroll
      for (int b = 0; b < 4; ++b) {
        long bn = b * 8 + n;
        u16 v = f2bf(ac[b] + bias);
        if (mat == 0)      a.PQ[(bn * 1025 + 1024) * 512 + ch] = v;
        else if (mat == 1) a.PK[(bn * 1025 + 1024) * 512 + ch] = v;
        else               a.PVt[(bn * 512 + ch) * 1088 + 1024] = v;
      }
    }
  } else {
    int t2 = wid - 12288;
    int mat = t2 >> 12, o2 = t2 & 4095, n = o2 >> 9, o = o2 & 511;
    const float* bsrc = (mat == 0) ? a.bq : (mat == 1) ? a.bk : a.bv;
    short8 wp = *(const short8*)(a.Wp + (long)mat * 262144 + o * 512 + lane * 8);
    const float* bb = bsrc + n * 512 + lane * 8;
    float4 b0 = *(const float4*)bb;
    float4 b1 = *(const float4*)(bb + 4);
    float bf8[8] = {b0.x, b0.y, b0.z, b0.w, b1.x, b1.y, b1.z, b1.w};
    float s = 0.f;
#pragma unroll
    for (int e = 0; e < 8; ++e) s += bf2f((u16)wp[e]) * bf8[e];
#pragma unroll
    for (int o1 = 32; o1 > 0; o1 >>= 1) s += __shfl_xor(s, o1, 64);
    if (lane == 0) {
      const float* bpp = (mat == 0) ? a.bpq : (mat == 1) ? a.bpk : a.bpv;
      a.bc[t2] = s + bpp[o];
    }
  }
}

// ---------------------------------------------------------------------------
// S edge (permuted order: cls = index 1024): S[1024][kv] kv<=1024 and
// S[q][1024] q<1024 -> 2049 dots of length 512 per head. One dot per thread.
// ---------------------------------------------------------------------------
__global__ __launch_bounds__(256) void s_edge(const u16* __restrict__ PQ,
                                              const u16* __restrict__ PK,
                                              u16* __restrict__ S, int nh) {
  int flat = blockIdx.x;                 // nh*8
  int head, seg;
  if (nh == 32) {
    int xcd = flat & 7, s = flat >> 3;   // s: 0..31
    head = xcd + 8 * (s >> 3);           // 0..31
    seg = s & 7;
  } else {
    head = flat >> 3;
    seg = flat & 7;
  }
  const u16* pq = PQ + (long)head * 1025 * 512;
  const u16* pk = PK + (long)head * 1025 * 512;
  u16* sh = S + (long)head * 1025 * 1088;
#pragma unroll
  for (int i = 0; i < 2; ++i) {
    int local = i * 256 + (int)threadIdx.x;
    if (local >= 257) continue;
    int e = seg * 257 + local;
    if (e >= 2049) continue;
    int q, kv;
    if (e < 1025) { q = 1024; kv = e; }
    else { q = e - 1025; kv = 1024; }
    const u16* a = pq + (long)q * 512;
    const u16* b = pk + (long)kv * 512;
    float acc = 0.f;
    for (int k8 = 0; k8 < 64; ++k8) {
      short8 av = *(const short8*)(a + k8 * 8);
      short8 bv = *(const short8*)(b + k8 * 8);
#pragma unroll
      for (int u = 0; u < 8; ++u) acc += bf2f((u16)av[u]) * bf2f((u16)bv[u]);
    }
    sh[(long)q * 1088 + kv] = f2bf(acc * 0.04419417382415922f);
  }
}

// ---------------------------------------------------------------------------
// Softmax: one WAVE per row, 4 rows/block. XCD head-grouped.
// ---------------------------------------------------------------------------
__global__ __launch_bounds__(256) void softmax_rows(u16* __restrict__ S) {
  int flat = blockIdx.x;
  int xcd = flat & 7, s0 = flat >> 3;
  int zi = s0 / 257, blk = s0 - zi * 257;
  int head = xcd + 8 * zi;
  int wv = threadIdx.x >> 6, lane = threadIdx.x & 63;
  int row_i = blk * 4 + wv;
  if (row_i > 1024) return;
  u16* row = S + ((long)head * 1025 + row_i) * 1088;
  float v[16];
  float mx = -1e30f;
#pragma unroll
  for (int i = 0; i < 4; ++i) {
    us4 p = *(const us4*)(row + i * 256 + lane * 4);
#pragma unroll
    for (int e = 0; e < 4; ++e) { v[i * 4 + e] = bf2f(p[e]); mx = fmaxf(mx, v[i * 4 + e]); }
  }
  float e1024 = (lane == 0) ? bf2f(row[1024]) : -1e30f;
  mx = fmaxf(mx, e1024);
  for (int o = 32; o > 0; o >>= 1) mx = fmaxf(mx, __shfl_xor(mx, o, 64));
  float s = 0.f;
#pragma unroll
  for (int i = 0; i < 16; ++i) { v[i] = __expf(v[i] - mx); s += v[i]; }
  e1024 = (lane == 0) ? __expf(e1024 - mx) : 0.f;
  s += e1024;
  for (int o = 32; o > 0; o >>= 1) s += __shfl_xor(s, o, 64);
  float inv = 1.0f / s;
#pragma unroll
  for (int i = 0; i < 4; ++i) {
    us4 q;
#pragma unroll
    for (int e = 0; e < 4; ++e) q[e] = f2bf(v[i * 4 + e] * inv);
    *(us4*)(row + i * 256 + lane * 4) = q;
  }
  if (lane < 16) {
    us4 q;
#pragma unroll
    for (int e = 0; e < 4; ++e) q[e] = 0;
    if (lane == 0) q[0] = f2bf(e1024 * inv);
    *(us4*)(row + 1024 + lane * 4) = q;
  }
}

// ---------------------------------------------------------------------------
// reduce2: out = p0+p1+p2+p3 + bd  (4 split-K partials).
// ---------------------------------------------------------------------------
__global__ __launch_bounds__(256) void reduce2(const float* __restrict__ part,
                                               const float* __restrict__ bd,
                                               float* __restrict__ out) {
  int t = blockIdx.x * 256 + threadIdx.x;    // < 524800
  long i = (long)t * 4;
  const long STR = 4100ll * 512;
  float4 a0 = *(const float4*)(part + i);
  float4 a1 = *(const float4*)(part + i + STR);
  float4 a2 = *(const float4*)(part + i + 2 * STR);
  float4 a3 = *(const float4*)(part + i + 3 * STR);
  float4 bb = *(const float4*)(bd + (int)(i & 511));
  float4 r;
  r.x = a0.x + a1.x + a2.x + a3.x + bb.x;
  r.y = a0.y + a1.y + a2.y + a3.y + bb.y;
  r.z = a0.z + a1.z + a2.z + a3.z + bb.z;
  r.w = a0.w + a1.w + a2.w + a3.w + bb.w;
  *(float4*)(out + i) = r;
}

// ---------------------------------------------------------------------------
// GEMM-BT: C[m][n] = sum_k A[m][k]*B[n][k], bf16, 128x128 tile, BK=64,
// staging XOR swizzle. Token order: cls at 1024 in PQ/PK/S/PVt.
// Modes:
//  0 PROJ : A=xb spatial rows (M=4096), B=[Wc q|k sections|Wqb], N=12288.
//           Sections (nt>>5): 0 PQ(+emb), 1 PK, 2 Q. Bias: bc / bq.
//  2 PVT  : A=xb spatial, B=Wc v-section -> PVt via transposed epilogue.
//           1D XCD-grouped, 1024 blocks.
//  3 S    : 1D XCD head-grouped; interior 8x8 tiles only
//  4 O    : 1D XCD head-grouped; S*PVt^T -> stacked (+Q resid), l=perm(q)
//  5 FIN  : A=stk, B=Wd, split-K x4 -> f32 partials (528 blocks, 2/CU)
//  6 FOLD : Wc = Wp·W per head (B k-slow: rotated-source staging + strided
//           ds_read_u16 B-frags).
// ---------------------------------------------------------------------------
struct GP {
  const u16* A; const u16* A2; const u16* B; const u16* B2;
  const float* c0; const float* c1; const float* c2;
  const float* emb; const u16* resid;
  u16* o0; u16* o1; u16* o2;
  u16* p0; u16* p1; u16* p2;
  float* of; int bz0;
};

template <int MODE>
__global__ __launch_bounds__(256) void gemm_bt(GP g) {
  constexpr int KLEN = (MODE == 5) ? 1024 : ((MODE == 4) ? 1088 : 512);
  constexpr int KITER = KLEN / 64;
  __shared__ u16 smem[16384];          // As | Bs staging; epilogue tile reuse
  u16* As = smem;
  u16* Bs = smem + 8192;
  const int tid = threadIdx.x;
  const int lane = tid & 63;
  const int wv = tid >> 6;
  const int wr = wv >> 1, wc = wv & 1;
  const int ccol = lane & 15;
  const int rgrp = lane >> 4;

  // Block -> (mt, nt, bz). XCD grouping (flat&7) for modes 2/3/4.
  int mt, nt, bz, mh = 0;
  if constexpr (MODE == 3 || MODE == 4) {
    constexpr int PER = (MODE == 3) ? 64 : 36;   // mode3: interior 8x8 only
    constexpr int NTW = (MODE == 3) ? 8 : 4;
    int flat = blockIdx.x;
    int xcd = flat & 7, s = flat >> 3;
    bz = xcd + 8 * (s / PER);
    int tile = s % PER;
    mt = tile / NTW;
    nt = tile % NTW;
  } else if constexpr (MODE == 2) {
    int flat = blockIdx.x;               // 1024 blocks
    int xcd = flat & 7, s = flat >> 3;   // s: 0..127
    bz = 0;
    mt = xcd * 4 + (s >> 5);             // 0..31
    nt = s & 31;                         // 0..31
  } else if constexpr (MODE == 6) {
    int flat = blockIdx.x;               // 384 blocks
    mh = flat >> 4;                      // mat*8 + head, 0..23
    int tile = flat & 15;
    mt = tile >> 2; nt = tile & 3; bz = 0;
  } else {
    mt = blockIdx.y; nt = blockIdx.x; bz = blockIdx.z;
  }
  const int gbz = g.bz0 + bz;

  const u16* Ap = g.A;
  const u16* Bp = g.B;
  if constexpr (MODE == 0) {
    if (nt >= 64) Bp = g.B2;             // Q section uses raw Wq
  }

  int a_row[4], b_row[4], kx[4];
#pragma unroll
  for (int c = 0; c < 4; ++c) {
    int idx = c * 256 + tid;
    int row = idx >> 3;                       // 0..127
    kx[c] = ((idx & 7) ^ (row & 7)) * 8;      // swizzled k-chunk offset (elems)
    {
      int r = mt * 128 + row;
      int off;
      if constexpr (MODE == 0 || MODE == 2) { off = ((r >> 10) * 1025 + 1 + (r & 1023)) * 512; }
      else if constexpr (MODE == 3) { off = gbz * (1025 * 512) + r * 512; }
      else if constexpr (MODE == 4) { r = r < 1024 ? r : 1024; off = bz * (1025 * 1088) + r * 1088; }
      else if constexpr (MODE == 6) { off = (mh >> 3) * 262144 + r * 512; }
      else { r = r < 4099 ? r : 4099; off = r * 4096; }       // MODE 5
      a_row[c] = off;
    }
    {
      int off;
      if constexpr (MODE == 6) {
        int rb = idx >> 4, s2 = idx & 15;           // [64 c-rows][16 chunks]
        int cg = (s2 - ((rb >> 3) << 1)) & 15;      // inverse 16-elem rotation
        off = mh * 262144 + rb * 512 + nt * 128 + cg * 8;
      } else {
        int r = nt * 128 + row;
        if constexpr (MODE == 0) { off = ((nt >= 64) ? (r - 8192) : r) * 512; }
        else if constexpr (MODE == 3) { off = gbz * (1025 * 512) + r * 512; }
        else if constexpr (MODE == 4) { off = gbz * (512 * 1088) + r * 1088; }
        else if constexpr (MODE == 5) { off = r * 4096; }
        else { off = r * 512; }                                 // MODE 2
      }
      b_row[c] = off;
    }
  }

  // Accumulators: modes 0/2 initialize with the per-column bias.
  floatx4 acc[4][4];
  {
    float binit[4] = {0.f, 0.f, 0.f, 0.f};
    if constexpr (MODE == 0) {
      int sec = nt >> 5;
      const float* bs = (sec < 2) ? (g.c0 + sec * 4096) : g.c1;
#pragma unroll
      for (int j = 0; j < 4; ++j) binit[j] = bs[(nt & 31) * 128 + wc * 64 + j * 16 + ccol];
    }
    if constexpr (MODE == 2) {
#pragma unroll
      for (int j = 0; j < 4; ++j) binit[j] = g.c0[nt * 128 + wc * 64 + j * 16 + ccol];
    }
#pragma unroll
    for (int i = 0; i < 4; ++i)
#pragma unroll
      for (int j = 0; j < 4; ++j)
#pragma unroll
        for (int rr = 0; rr < 4; ++rr) acc[i][j][rr] = binit[j];
  }

  const int kbase = (MODE == 5) ? bz * 1024 : 0;
  const int l15 = lane & 15;
  const int lq = lane >> 4;
  const int l7 = lane & 7;

  for (int kt = 0; kt < KITER; ++kt) {
    const int k0 = kbase + kt * 64;
#pragma unroll
    for (int c = 0; c < 4; ++c)
      gld_lds16(Ap + a_row[c] + k0 + kx[c], (char*)As + (c * 256 + wv * 64) * 16);
#pragma unroll
    for (int c = 0; c < 4; ++c) {
      if constexpr (MODE == 6)
        gld_lds16(Bp + b_row[c] + k0 * 512, (char*)Bs + (c * 256 + wv * 64) * 16);
      else
        gld_lds16(Bp + b_row[c] + k0 + kx[c], (char*)Bs + (c * 256 + wv * 64) * 16);
    }
    __syncthreads();
#pragma unroll
    for (int ks = 0; ks < 2; ++ks) {
      const int ch = ((ks * 4 + lq) ^ l7) * 8;
      short8 af[4], bfr[4];
#pragma unroll
      for (int i = 0; i < 4; ++i)
        af[i] = *(const short8*)(As + (wr * 64 + i * 16 + l15) * 64 + ch);
      if constexpr (MODE == 6) {
        // B' is [k=64][i=128] with 16-elem rotation per k-octet:
        // elem(k,i) at k*128 + ((i + 16*(k>>3)) & 127).
#pragma unroll
        for (int j = 0; j < 4; ++j) {
          int ro = ((wc * 64 + j * 16 + l15) + ((ks * 4 + lq) << 4)) & 127;
          const u16* bp2 = Bs + (ks * 32 + lq * 8) * 128 + ro;
          short8 tv;
#pragma unroll
          for (int e = 0; e < 8; ++e) tv[e] = (short)bp2[e * 128];
          bfr[j] = tv;
        }
      } else {
#pragma unroll
        for (int j = 0; j < 4; ++j)
          bfr[j] = *(const short8*)(Bs + (wc * 64 + j * 16 + l15) * 64 + ch);
      }
#pragma unroll
      for (int i = 0; i < 4; ++i)
#pragma unroll
        for (int j = 0; j < 4; ++j)
          acc[i][j] = __builtin_amdgcn_mfma_f32_16x16x32_bf16(af[i], bfr[j], acc[i][j], 0, 0, 0);
    }
    __syncthreads();
  }

  // ---- Epilogue ---- (C/D frag: col = lane&15, row = (lane>>4)*4 + reg)
  if constexpr (MODE == 2) {
    // PVt: LDS-transposed epilogue [ch_local][sp_local], vector store
    // along sp (spatial at offset 0 in permuted PVt).
#pragma unroll
    for (int i = 0; i < 4; ++i)
#pragma unroll
      for (int j = 0; j < 4; ++j)
#pragma unroll
        for (int rr = 0; rr < 4; ++rr) {
          int lr2 = wc * 64 + j * 16 + ccol;            // ch-local
          int lc2 = wr * 64 + i * 16 + rgrp * 4 + rr;   // sp-local
          smem[lr2 * 128 + (lc2 ^ ((lr2 & 15) << 3))] = f2bf(acc[i][j][rr]);
        }
    __syncthreads();
    {
      int b = mt >> 3, sp0 = (mt & 7) * 128;
      int n = nt >> 2, ch0 = (nt & 3) * 128;
      long bn = b * 8 + n;
#pragma unroll
      for (int q = 0; q < 8; ++q) {
        int cid = q * 256 + tid;
        int r = cid >> 4;                 // ch-local 0..127
        int c = cid & 15;                 // sp chunk
        int pc = c ^ (r & 15);
        short8 val = *(const short8*)(smem + r * 128 + pc * 8);
        *(short8*)(g.o0 + (bn * 512 + ch0 + r) * 1088 + sp0 + c * 8) = val;
      }
    }
  } else if constexpr (MODE == 0 || MODE == 3 || MODE == 4 || MODE == 6) {
#pragma unroll
    for (int i = 0; i < 4; ++i)
#pragma unroll
      for (int j = 0; j < 4; ++j)
#pragma unroll
        for (int rr = 0; rr < 4; ++rr) {
          int lr = wr * 64 + i * 16 + rgrp * 4 + rr;
          int lc = wc * 64 + j * 16 + ccol;
          float v = acc[i][j][rr];
          if constexpr (MODE == 3) v *= 0.04419417382415922f;
          smem[lr * 128 + (lc ^ (rgrp << 4))] = f2bf(v);
        }
    __syncthreads();
#pragma unroll
    for (int q = 0; q < 8; ++q) {
      int cid = q * 256 + tid;
      int r = cid >> 4;                 // 0..127
      int c = cid & 15;                 // chunk
      int pc = c ^ ((((unsigned)r >> 2) & 3) << 1);
      short8 val = *(const short8*)(smem + r * 128 + pc * 8);
      int grow = mt * 128 + r;
      if constexpr (MODE == 0) {
        const int sec = nt >> 5;
        int b = grow >> 10, sp = grow & 1023;   // grow in 0..4095
        int gcol = (nt & 31) * 128 + c * 8;     // 0..4095 (n, ch)
        int n = gcol >> 9, ch2 = gcol & 511;
        long bn = b * 8 + n;
        if (sec == 0) {
          const float* ep = g.emb + sp * 512 + ch2;
          float4 e0 = *(const float4*)ep;
          float4 e1 = *(const float4*)(ep + 4);
          float ee[8] = {e0.x, e0.y, e0.z, e0.w, e1.x, e1.y, e1.z, e1.w};
          short8 outv;
#pragma unroll
          for (int e = 0; e < 8; ++e) outv[e] = (short)f2bf(bf2f((u16)val[e]) + ee[e]);
          *(short8*)(g.o0 + (bn * 1025 + sp) * 512 + ch2) = outv;        // PQ sp
        } else if (sec == 1) {
          *(short8*)(g.o1 + (bn * 1025 + sp) * 512 + ch2) = val;         // PK sp
        } else {
          *(short8*)(g.o2 + (bn * 1025 + 1 + sp) * 512 + ch2) = val;     // Q (orig order)
        }
      } else if constexpr (MODE == 3) {
        // interior only: grow < 1024, gcol < 1024 guaranteed
        *(short8*)(g.o0 + ((long)bz * 1025 + grow) * 1088 + nt * 128 + c * 8) = val;
      } else if constexpr (MODE == 6) {
        *(short8*)(g.o0 + ((long)(mh * 512) + grow) * 512 + nt * 128 + c * 8) = val;
      } else {  // MODE 4
        if (grow <= 1024) {
          int gcol0 = nt * 128 + c * 8;          // 0..511
          short8 outv = val;
          int l = (grow == 1024) ? 0 : grow + 1; // permuted q -> original l
          if (grow < 1024) {                     // spatial: add Q residual
            short8 rs = *(const short8*)(g.resid + ((long)gbz * 1025 + l) * 512 + gcol0);
#pragma unroll
            for (int e = 0; e < 8; ++e)
              outv[e] = (short)f2bf(bf2f((u16)val[e]) + bf2f((u16)rs[e]));
          }
          int b = gbz >> 3, n = gbz & 7;
          *(short8*)(g.o0 + (((long)b * 1025 + l) * 8 + n) * 512 + gcol0) = outv;
        }
      }
    }
  } else {
    // Scalar epilogue for mode 5 (f32 partials).
#pragma unroll
    for (int i = 0; i < 4; ++i) {
#pragma unroll
      for (int j = 0; j < 4; ++j) {
        const int gcol = nt * 128 + wc * 64 + j * 16 + ccol;
#pragma unroll
        for (int rr = 0; rr < 4; ++rr) {
          const int grow = mt * 128 + wr * 64 + i * 16 + rgrp * 4 + rr;
          if (grow < 4100)
            g.of[((long)bz * 4100 + grow) * 512 + gcol] = acc[i][j][rr];
        }
      }
    }
  }
}

// ---------------------------------------------------------------------------
extern "C" void kernel_launch(void* const* d_in, const int* in_sizes, int n_in,
                              void* d_out, int out_size, void* d_ws, size_t ws_size,
                              hipStream_t stream) {
  const float* x   = (const float*)d_in[0];
  const float* Wq  = (const float*)d_in[1];
  const float* bq  = (const float*)d_in[2];
  const float* Wk  = (const float*)d_in[3];
  const float* bk  = (const float*)d_in[4];
  const float* Wv  = (const float*)d_in[5];
  const float* bv  = (const float*)d_in[6];
  const float* Wpq = (const float*)d_in[7];
  const float* bpq = (const float*)d_in[8];
  const float* Wpk = (const float*)d_in[9];
  const float* bpk = (const float*)d_in[10];
  const float* Wpv = (const float*)d_in[11];
  const float* bpv = (const float*)d_in[12];
  const float* Wd  = (const float*)d_in[13];
  const float* bd  = (const float*)d_in[14];
  float* out = (float*)d_out;

  char* ws = (char*)d_ws;
  size_t off = 0;
  auto alloc = [&](size_t bytes) {
    char* p = ws + off;
    off += (bytes + 255) & ~(size_t)255;
    return p;
  };
  // Persistent through attention:
  u16* Wpqb = (u16*)alloc(512ull * 512 * 2);          // contiguous triple
  u16* Wpkb = (u16*)alloc(512ull * 512 * 2);
  u16* Wpvb = (u16*)alloc(512ull * 512 * 2);
  u16* Wdb  = (u16*)alloc(4096ull * 512 * 2);
  u16* Q    = (u16*)alloc(32ull * 1025 * 512 * 2);
  u16* PQ   = (u16*)alloc(32ull * 1025 * 512 * 2);   // later: 4x f32 partials
  u16* PK   = (u16*)alloc(32ull * 1025 * 512 * 2);   // later: stk (nchunk=1)
  u16* PVt  = (u16*)alloc(32ull * 512 * 1088 * 2);
  // Dead-by-attention group (S aliases from here):
  size_t s_off = off;
  u16* xb   = (u16*)alloc(4100ull * 512 * 2);
  u16* Wqb  = (u16*)alloc(4096ull * 512 * 2);   // Wqb|Wkb|Wvb contiguous
  u16* Wkb  = (u16*)alloc(4096ull * 512 * 2);
  u16* Wvb  = (u16*)alloc(4096ull * 512 * 2);
  u16* Wc   = (u16*)alloc(3ull * 4096 * 512 * 2);     // folded Wp·W
  float* bc = (float*)alloc(3ull * 4096 * 4);         // folded biases
  float* embp = (float*)alloc(1024ull * 512 * 4);
  size_t fixed_need = off;
  u16* S = (u16*)(ws + s_off);
  float* part = (float*)PQ;   // PQ dead before partials written (4x fits exactly)
  (void)in_sizes; (void)n_in; (void)out_size; (void)Wkb; (void)Wvb;
  (void)Wpkb; (void)Wpvb;

  const size_t sbytes = 1025ull * 1088 * 2;
  size_t need1 = s_off + 32ull * sbytes;
  size_t need2 = s_off + 16ull * sbytes;
  size_t stk4_off = s_off + ((8ull * sbytes + 255) & ~(size_t)255);
  size_t need4 = stk4_off + 4100ull * 4096 * 2;
  int nchunk;
  u16* stk;
  if (ws_size >= need1)      { nchunk = 1; stk = PK; }   // PK dead after mode 3
  else if (ws_size >= need2 && ws_size >= fixed_need) { nchunk = 2; stk = PK; }
  else if (ws_size >= need4 && ws_size >= fixed_need) {
    nchunk = 4; stk = (u16*)(ws + stk4_off);
  } else return;  // clean fail instead of GPU fault
  if (nchunk == 2) {
    size_t stk2_off = s_off + ((16ull * sbytes + 255) & ~(size_t)255);
    if (ws_size >= stk2_off + 4100ull * 4096 * 2) stk = (u16*)(ws + stk2_off);
    else {
      nchunk = 4;
      if (ws_size >= need4) stk = (u16*)(ws + stk4_off);
      else return;
    }
  }
  int hpc = 32 / nchunk;

  // 1) dtype conversions + pos-embed (one launch)
  CvtArgs ca;
  ca.src[0] = x;   ca.dst[0] = xb;   ca.n4[0] = 4100 * 512 / 4;
  ca.src[1] = Wq;  ca.dst[1] = Wqb;  ca.n4[1] = 4096 * 512 / 4;
  ca.src[2] = Wk;  ca.dst[2] = Wkb;  ca.n4[2] = 4096 * 512 / 4;
  ca.src[3] = Wv;  ca.dst[3] = Wvb;  ca.n4[3] = 4096 * 512 / 4;
  ca.src[4] = Wpq; ca.dst[4] = Wpqb; ca.n4[4] = 512 * 512 / 4;
  ca.src[5] = Wpk; ca.dst[5] = Wpkb; ca.n4[5] = 512 * 512 / 4;
  ca.src[6] = Wpv; ca.dst[6] = Wpvb; ca.n4[6] = 512 * 512 / 4;
  ca.src[7] = Wd;  ca.dst[7] = Wdb;  ca.n4[7] = 512 * 4096 / 4;
  int total4 = 0;
  for (int s = 0; s < 8; ++s) total4 += ca.n4[s];
  int grid1 = (total4 + 1024 * 512 / 4 + 255) / 256;
  cvt_all<<<grid1, 256, 0, stream>>>(ca, total4, embp);

  // 2a) weight fold: Wc[mat][n][o][i] = sum_c Wp_mat[o][c]·W[mat*4096+n*512+c][i]
  {
    GP g = {};
    g.A = Wpqb; g.B = Wqb; g.o0 = Wc;
    gemm_bt<6><<<dim3(384, 1, 1), 256, 0, stream>>>(g);
  }
  // 2b) cls rows of PQ/PK/PVt + folded pool biases bc (wave-parallel)
  {
    CF cf;
    cf.W = Wqb; cf.Wp = Wpqb; cf.xb = xb;
    cf.bq = bq; cf.bk = bk; cf.bv = bv;
    cf.bpq = bpq; cf.bpk = bpk; cf.bpv = bpv;
    cf.PQ = PQ; cf.PK = PK; cf.PVt = PVt; cf.bc = bc;
    cls_fold<<<6144, 256, 0, stream>>>(cf);
  }

  // 3) fused projection+pool: x -> PQ(+emb) | PK | Q (spatial rows)
  {
    GP g = {};
    g.A = xb; g.B = Wc; g.B2 = Wqb;
    g.c0 = bc; g.c1 = bq; g.emb = embp;
    g.o0 = PQ; g.o1 = PK; g.o2 = Q;
    gemm_bt<0><<<dim3(96, 32, 1), 256, 0, stream>>>(g);
  }
  // 3b) PVt: x · Wc_v^T via transposed epilogue
  {
    GP g = {};
    g.A = xb; g.B = Wc + 8192 * 512; g.c0 = bc + 8192; g.o0 = PVt;
    gemm_bt<2><<<dim3(1024, 1, 1), 256, 0, stream>>>(g);
  }
  // xb, Wq/k/v, Wc, bc, embp now dead -> S aliases them.

  // 4) attention: interior S tiles + S edge -> softmax -> O (+Q resid).
  for (int c = 0; c < nchunk; ++c) {
    GP g3 = {}; g3.A = PQ; g3.B = PK; g3.o0 = S; g3.bz0 = c * hpc;
    gemm_bt<3><<<dim3(64 * hpc, 1, 1), 256, 0, stream>>>(g3);
    s_edge<<<hpc * 8, 256, 0, stream>>>(
        PQ + (long)c * hpc * 1025 * 512, PK + (long)c * hpc * 1025 * 512, S, hpc);
    softmax_rows<<<257 * hpc, 256, 0, stream>>>(S);
    GP g4 = {}; g4.A = S; g4.B = PVt; g4.resid = Q; g4.o0 = stk; g4.bz0 = c * hpc;
    gemm_bt<4><<<dim3(36 * hpc, 1, 1), 256, 0, stream>>>(g4);
  }
  // PQ dead -> 4x f32 partials alias it (33.6 MB exactly).

  // 5) final projection, split-K x4 -> partials, then reduce (+bias)
  {
    GP g = {}; g.A = stk; g.B = Wdb; g.of = part;
    gemm_bt<5><<<dim3(4, 33, 4), 256, 0, stream>>>(g);
  }
  reduce2<<<(4100 * 512 / 4 + 255) / 256, 256, 0, stream>>>(part, bd, out);
}

// Round 20
// 428.002 us; speedup vs baseline: 1.1812x; 1.0060x over previous
//
#include <hip/hip_runtime.h>

// ---------------------------------------------------------------------------
// MultiHeadPooledSelfAttention on gfx950.
// R23 = exact R19 (best measured, 430.2 us). Locks the measured plateau:
//   * pooler fold Wc=Wp·W (mode-6): KEPT (-13 us vs baseline 443.4)
//   * wave-parallel cls_fold: KEPT (R18's thread-per-dot was uncoalesced)
//   * PVt split into mode-2 (avoids R18's 116-VGPR merged epilogue): KEPT
//   * Q-residual fold (R20/R21): REVERTED (measured +13 us net)
//   * mode-5 split-K x4 (R22): REVERTED (measured neutral; x2 has half the
//     partial traffic)
// Remaining lever is the 8-phase 256^2 counted-vmcnt template (sync-structure
// rewrite; not attempted blind per race-screen discipline).
// ---------------------------------------------------------------------------

typedef unsigned short u16;
typedef __attribute__((ext_vector_type(8))) short short8;   // 8 x bf16
typedef __attribute__((ext_vector_type(4))) float floatx4;
typedef __attribute__((ext_vector_type(4))) unsigned short us4;

__device__ __forceinline__ u16 f2bf(float f) {
  union { float f; unsigned u; } x; x.f = f;
  unsigned r = (x.u + 0x7fffu + ((x.u >> 16) & 1u)) >> 16;
  return (u16)r;
}
__device__ __forceinline__ float bf2f(u16 u) {
  union { unsigned u; float f; } x; x.u = ((unsigned)u) << 16;
  return x.f;
}

__device__ __forceinline__ void gld_lds16(const void* g, void* l) {
  __builtin_amdgcn_global_load_lds(
      (const __attribute__((address_space(1))) void*)g,
      (__attribute__((address_space(3))) void*)l, 16, 0, 0);
}

// ---------------------------------------------------------------------------
struct CvtArgs { const float* src[8]; u16* dst[8]; int n4[8]; };

__global__ __launch_bounds__(256) void cvt_all(CvtArgs a, int total4, float* __restrict__ e) {
  int t = blockIdx.x * 256 + threadIdx.x;
  if (t >= total4) {
    int et = (t - total4) * 4;                  // emb flat base, < 1024*512
    if (et >= 1024 * 512) return;
#pragma unroll
    for (int u = 0; u < 4; ++u) {
      int idx = et + u;
      int c = idx & 511, sp = idx >> 9;
      int y = sp >> 5, xg = sp & 31;
      int j = c & 127, seg = c >> 7;
      float omega = expf(-(float)j * (9.210340371976184f / 128.f));
      float arg = (float)((seg < 2) ? y : xg) * omega;
      e[idx] = (seg & 1) ? cosf(arg) : sinf(arg);
    }
    return;
  }
#pragma unroll
  for (int s = 0; s < 8; ++s) {
    if (t < a.n4[s]) {
      const float* sp = a.src[s] + (long)t * 4;
      u16* dp = a.dst[s] + (long)t * 4;
      float4 v = *(const float4*)sp;
      dp[0] = f2bf(v.x); dp[1] = f2bf(v.y); dp[2] = f2bf(v.z); dp[3] = f2bf(v.w);
      return;
    }
    t -= a.n4[s];
  }
}

// ---------------------------------------------------------------------------
// cls_fold (wave-parallel): one WAVE per dot.
//  wid < 12288: cls rows  Q/K/V_cls[b][o2] = x[b,0,:]·W[o2,:] + b[o2]
//               -> PQ/PK row 1024, PVt col 1024 (4 batches per wave).
//  else       : folded pool bias bc[t2] = Wp[o,:]·b[n*512..] + bp[o].
// Lane l loads elems l*8..l*8+7 (coalesced 1 KB per wave); shfl_xor reduce.
// Grid: 6144 blocks x 256 (4 waves/block, 24576 waves total).
// ---------------------------------------------------------------------------
struct CF {
  const u16* W;      // Wqb|Wkb|Wvb contiguous
  const u16* Wp;     // Wpqb|Wpkb|Wpvb contiguous
  const u16* xb;
  const float *bq, *bk, *bv, *bpq, *bpk, *bpv;
  u16 *PQ, *PK, *PVt;
  float* bc;
};

__global__ __launch_bounds__(256) void cls_fold(CF a) {
  int wid = blockIdx.x * 4 + (threadIdx.x >> 6);   // 0..24575
  int lane = threadIdx.x & 63;
  if (wid < 12288) {
    int mat = wid >> 12, o2 = wid & 4095, n = o2 >> 9, ch = o2 & 511;
    short8 wv = *(const short8*)(a.W + (long)wid * 512 + lane * 8);
    float wf[8];
#pragma unroll
    for (int e = 0; e < 8; ++e) wf[e] = bf2f((u16)wv[e]);
    float ac[4] = {0.f, 0.f, 0.f, 0.f};
#pragma unroll
    for (int b = 0; b < 4; ++b) {
      short8 xv = *(const short8*)(a.xb + ((long)b * 1025) * 512 + lane * 8);
#pragma unroll
      for (int e = 0; e < 8; ++e) ac[b] += wf[e] * bf2f((u16)xv[e]);
    }
#pragma unroll
    for (int o = 32; o > 0; o >>= 1)
#pragma unroll
      for (int b = 0; b < 4; ++b) ac[b] += __shfl_xor(ac[b], o, 64);
    if (lane == 0) {
      const float* bsrc = (mat == 0) ? a.bq : (mat == 1) ? a.bk : a.bv;
      float bias = bsrc[o2];
#pragma unroll
      for (int b = 0; b < 4; ++b) {
        long bn = b * 8 + n;
        u16 v = f2bf(ac[b] + bias);
        if (mat == 0)      a.PQ[(bn * 1025 + 1024) * 512 + ch] = v;
        else if (mat == 1) a.PK[(bn * 1025 + 1024) * 512 + ch] = v;
        else               a.PVt[(bn * 512 + ch) * 1088 + 1024] = v;
      }
    }
  } else {
    int t2 = wid - 12288;
    int mat = t2 >> 12, o2 = t2 & 4095, n = o2 >> 9, o = o2 & 511;
    const float* bsrc = (mat == 0) ? a.bq : (mat == 1) ? a.bk : a.bv;
    short8 wp = *(const short8*)(a.Wp + (long)mat * 262144 + o * 512 + lane * 8);
    const float* bb = bsrc + n * 512 + lane * 8;
    float4 b0 = *(const float4*)bb;
    float4 b1 = *(const float4*)(bb + 4);
    float bf8[8] = {b0.x, b0.y, b0.z, b0.w, b1.x, b1.y, b1.z, b1.w};
    float s = 0.f;
#pragma unroll
    for (int e = 0; e < 8; ++e) s += bf2f((u16)wp[e]) * bf8[e];
#pragma unroll
    for (int o1 = 32; o1 > 0; o1 >>= 1) s += __shfl_xor(s, o1, 64);
    if (lane == 0) {
      const float* bpp = (mat == 0) ? a.bpq : (mat == 1) ? a.bpk : a.bpv;
      a.bc[t2] = s + bpp[o];
    }
  }
}

// ---------------------------------------------------------------------------
// S edge (permuted order: cls = index 1024): S[1024][kv] kv<=1024 and
// S[q][1024] q<1024 -> 2049 dots of length 512 per head. One dot per thread.
// ---------------------------------------------------------------------------
__global__ __launch_bounds__(256) void s_edge(const u16* __restrict__ PQ,
                                              const u16* __restrict__ PK,
                                              u16* __restrict__ S, int nh) {
  int flat = blockIdx.x;                 // nh*8
  int head, seg;
  if (nh == 32) {
    int xcd = flat & 7, s = flat >> 3;   // s: 0..31
    head = xcd + 8 * (s >> 3);           // 0..31
    seg = s & 7;
  } else {
    head = flat >> 3;
    seg = flat & 7;
  }
  const u16* pq = PQ + (long)head * 1025 * 512;
  const u16* pk = PK + (long)head * 1025 * 512;
  u16* sh = S + (long)head * 1025 * 1088;
#pragma unroll
  for (int i = 0; i < 2; ++i) {
    int local = i * 256 + (int)threadIdx.x;
    if (local >= 257) continue;
    int e = seg * 257 + local;
    if (e >= 2049) continue;
    int q, kv;
    if (e < 1025) { q = 1024; kv = e; }
    else { q = e - 1025; kv = 1024; }
    const u16* a = pq + (long)q * 512;
    const u16* b = pk + (long)kv * 512;
    float acc = 0.f;
    for (int k8 = 0; k8 < 64; ++k8) {
      short8 av = *(const short8*)(a + k8 * 8);
      short8 bv = *(const short8*)(b + k8 * 8);
#pragma unroll
      for (int u = 0; u < 8; ++u) acc += bf2f((u16)av[u]) * bf2f((u16)bv[u]);
    }
    sh[(long)q * 1088 + kv] = f2bf(acc * 0.04419417382415922f);
  }
}

// ---------------------------------------------------------------------------
// Softmax: one WAVE per row, 4 rows/block. XCD head-grouped.
// ---------------------------------------------------------------------------
__global__ __launch_bounds__(256) void softmax_rows(u16* __restrict__ S) {
  int flat = blockIdx.x;
  int xcd = flat & 7, s0 = flat >> 3;
  int zi = s0 / 257, blk = s0 - zi * 257;
  int head = xcd + 8 * zi;
  int wv = threadIdx.x >> 6, lane = threadIdx.x & 63;
  int row_i = blk * 4 + wv;
  if (row_i > 1024) return;
  u16* row = S + ((long)head * 1025 + row_i) * 1088;
  float v[16];
  float mx = -1e30f;
#pragma unroll
  for (int i = 0; i < 4; ++i) {
    us4 p = *(const us4*)(row + i * 256 + lane * 4);
#pragma unroll
    for (int e = 0; e < 4; ++e) { v[i * 4 + e] = bf2f(p[e]); mx = fmaxf(mx, v[i * 4 + e]); }
  }
  float e1024 = (lane == 0) ? bf2f(row[1024]) : -1e30f;
  mx = fmaxf(mx, e1024);
  for (int o = 32; o > 0; o >>= 1) mx = fmaxf(mx, __shfl_xor(mx, o, 64));
  float s = 0.f;
#pragma unroll
  for (int i = 0; i < 16; ++i) { v[i] = __expf(v[i] - mx); s += v[i]; }
  e1024 = (lane == 0) ? __expf(e1024 - mx) : 0.f;
  s += e1024;
  for (int o = 32; o > 0; o >>= 1) s += __shfl_xor(s, o, 64);
  float inv = 1.0f / s;
#pragma unroll
  for (int i = 0; i < 4; ++i) {
    us4 q;
#pragma unroll
    for (int e = 0; e < 4; ++e) q[e] = f2bf(v[i * 4 + e] * inv);
    *(us4*)(row + i * 256 + lane * 4) = q;
  }
  if (lane < 16) {
    us4 q;
#pragma unroll
    for (int e = 0; e < 4; ++e) q[e] = 0;
    if (lane == 0) q[0] = f2bf(e1024 * inv);
    *(us4*)(row + 1024 + lane * 4) = q;
  }
}

// ---------------------------------------------------------------------------
// reduce2: out = p0+p1 + bd  (2 split-K partials).
// ---------------------------------------------------------------------------
__global__ __launch_bounds__(256) void reduce2(const float* __restrict__ part,
                                               const float* __restrict__ bd,
                                               float* __restrict__ out) {
  int t = blockIdx.x * 256 + threadIdx.x;    // < 524800
  long i = (long)t * 4;
  const long STR = 4100ll * 512;
  float4 a = *(const float4*)(part + i);
  float4 b = *(const float4*)(part + i + STR);
  float4 bb = *(const float4*)(bd + (int)(i & 511));
  float4 r;
  r.x = a.x + b.x + bb.x;
  r.y = a.y + b.y + bb.y;
  r.z = a.z + b.z + bb.z;
  r.w = a.w + b.w + bb.w;
  *(float4*)(out + i) = r;
}

// ---------------------------------------------------------------------------
// GEMM-BT: C[m][n] = sum_k A[m][k]*B[n][k], bf16, 128x128 tile, BK=64,
// staging XOR swizzle. Token order: cls at 1024 in PQ/PK/S/PVt.
// Modes:
//  0 PROJ : A=xb spatial rows (M=4096), B=[Wc q|k sections|Wqb], N=12288.
//           Sections (nt>>5): 0 PQ(+emb), 1 PK, 2 Q. Bias: bc / bq.
//  2 PVT  : A=xb spatial, B=Wc v-section -> PVt via transposed epilogue.
//           1D XCD-grouped, 1024 blocks.
//  3 S    : 1D XCD head-grouped; interior 8x8 tiles only
//  4 O    : 1D XCD head-grouped; S*PVt^T -> stacked (+Q resid), l=perm(q)
//  5 FIN  : A=stk, B=Wd, split-K x2 -> f32 partials
//  6 FOLD : Wc = Wp·W per head (B k-slow: rotated-source staging + strided
//           ds_read_u16 B-frags).
// ---------------------------------------------------------------------------
struct GP {
  const u16* A; const u16* A2; const u16* B; const u16* B2;
  const float* c0; const float* c1; const float* c2;
  const float* emb; const u16* resid;
  u16* o0; u16* o1; u16* o2;
  u16* p0; u16* p1; u16* p2;
  float* of; int bz0;
};

template <int MODE>
__global__ __launch_bounds__(256) void gemm_bt(GP g) {
  constexpr int KLEN = (MODE == 5) ? 2048 : ((MODE == 4) ? 1088 : 512);
  constexpr int KITER = KLEN / 64;
  __shared__ u16 smem[16384];          // As | Bs staging; epilogue tile reuse
  u16* As = smem;
  u16* Bs = smem + 8192;
  const int tid = threadIdx.x;
  const int lane = tid & 63;
  const int wv = tid >> 6;
  const int wr = wv >> 1, wc = wv & 1;
  const int ccol = lane & 15;
  const int rgrp = lane >> 4;

  // Block -> (mt, nt, bz). XCD grouping (flat&7) for modes 2/3/4.
  int mt, nt, bz, mh = 0;
  if constexpr (MODE == 3 || MODE == 4) {
    constexpr int PER = (MODE == 3) ? 64 : 36;   // mode3: interior 8x8 only
    constexpr int NTW = (MODE == 3) ? 8 : 4;
    int flat = blockIdx.x;
    int xcd = flat & 7, s = flat >> 3;
    bz = xcd + 8 * (s / PER);
    int tile = s % PER;
    mt = tile / NTW;
    nt = tile % NTW;
  } else if constexpr (MODE == 2) {
    int flat = blockIdx.x;               // 1024 blocks
    int xcd = flat & 7, s = flat >> 3;   // s: 0..127
    bz = 0;
    mt = xcd * 4 + (s >> 5);             // 0..31
    nt = s & 31;                         // 0..31
  } else if constexpr (MODE == 6) {
    int flat = blockIdx.x;               // 384 blocks
    mh = flat >> 4;                      // mat*8 + head, 0..23
    int tile = flat & 15;
    mt = tile >> 2; nt = tile & 3; bz = 0;
  } else {
    mt = blockIdx.y; nt = blockIdx.x; bz = blockIdx.z;
  }
  const int gbz = g.bz0 + bz;

  const u16* Ap = g.A;
  const u16* Bp = g.B;
  if constexpr (MODE == 0) {
    if (nt >= 64) Bp = g.B2;             // Q section uses raw Wq
  }

  int a_row[4], b_row[4], kx[4];
#pragma unroll
  for (int c = 0; c < 4; ++c) {
    int idx = c * 256 + tid;
    int row = idx >> 3;                       // 0..127
    kx[c] = ((idx & 7) ^ (row & 7)) * 8;      // swizzled k-chunk offset (elems)
    {
      int r = mt * 128 + row;
      int off;
      if constexpr (MODE == 0 || MODE == 2) { off = ((r >> 10) * 1025 + 1 + (r & 1023)) * 512; }
      else if constexpr (MODE == 3) { off = gbz * (1025 * 512) + r * 512; }
      else if constexpr (MODE == 4) { r = r < 1024 ? r : 1024; off = bz * (1025 * 1088) + r * 1088; }
      else if constexpr (MODE == 6) { off = (mh >> 3) * 262144 + r * 512; }
      else { r = r < 4099 ? r : 4099; off = r * 4096; }       // MODE 5
      a_row[c] = off;
    }
    {
      int off;
      if constexpr (MODE == 6) {
        int rb = idx >> 4, s2 = idx & 15;           // [64 c-rows][16 chunks]
        int cg = (s2 - ((rb >> 3) << 1)) & 15;      // inverse 16-elem rotation
        off = mh * 262144 + rb * 512 + nt * 128 + cg * 8;
      } else {
        int r = nt * 128 + row;
        if constexpr (MODE == 0) { off = ((nt >= 64) ? (r - 8192) : r) * 512; }
        else if constexpr (MODE == 3) { off = gbz * (1025 * 512) + r * 512; }
        else if constexpr (MODE == 4) { off = gbz * (512 * 1088) + r * 1088; }
        else if constexpr (MODE == 5) { off = r * 4096; }
        else { off = r * 512; }                                 // MODE 2
      }
      b_row[c] = off;
    }
  }

  // Accumulators: modes 0/2 initialize with the per-column bias.
  floatx4 acc[4][4];
  {
    float binit[4] = {0.f, 0.f, 0.f, 0.f};
    if constexpr (MODE == 0) {
      int sec = nt >> 5;
      const float* bs = (sec < 2) ? (g.c0 + sec * 4096) : g.c1;
#pragma unroll
      for (int j = 0; j < 4; ++j) binit[j] = bs[(nt & 31) * 128 + wc * 64 + j * 16 + ccol];
    }
    if constexpr (MODE == 2) {
#pragma unroll
      for (int j = 0; j < 4; ++j) binit[j] = g.c0[nt * 128 + wc * 64 + j * 16 + ccol];
    }
#pragma unroll
    for (int i = 0; i < 4; ++i)
#pragma unroll
      for (int j = 0; j < 4; ++j)
#pragma unroll
        for (int rr = 0; rr < 4; ++rr) acc[i][j][rr] = binit[j];
  }

  const int kbase = (MODE == 5) ? bz * 2048 : 0;
  const int l15 = lane & 15;
  const int lq = lane >> 4;
  const int l7 = lane & 7;

  for (int kt = 0; kt < KITER; ++kt) {
    const int k0 = kbase + kt * 64;
#pragma unroll
    for (int c = 0; c < 4; ++c)
      gld_lds16(Ap + a_row[c] + k0 + kx[c], (char*)As + (c * 256 + wv * 64) * 16);
#pragma unroll
    for (int c = 0; c < 4; ++c) {
      if constexpr (MODE == 6)
        gld_lds16(Bp + b_row[c] + k0 * 512, (char*)Bs + (c * 256 + wv * 64) * 16);
      else
        gld_lds16(Bp + b_row[c] + k0 + kx[c], (char*)Bs + (c * 256 + wv * 64) * 16);
    }
    __syncthreads();
#pragma unroll
    for (int ks = 0; ks < 2; ++ks) {
      const int ch = ((ks * 4 + lq) ^ l7) * 8;
      short8 af[4], bfr[4];
#pragma unroll
      for (int i = 0; i < 4; ++i)
        af[i] = *(const short8*)(As + (wr * 64 + i * 16 + l15) * 64 + ch);
      if constexpr (MODE == 6) {
        // B' is [k=64][i=128] with 16-elem rotation per k-octet:
        // elem(k,i) at k*128 + ((i + 16*(k>>3)) & 127).
#pragma unroll
        for (int j = 0; j < 4; ++j) {
          int ro = ((wc * 64 + j * 16 + l15) + ((ks * 4 + lq) << 4)) & 127;
          const u16* bp2 = Bs + (ks * 32 + lq * 8) * 128 + ro;
          short8 tv;
#pragma unroll
          for (int e = 0; e < 8; ++e) tv[e] = (short)bp2[e * 128];
          bfr[j] = tv;
        }
      } else {
#pragma unroll
        for (int j = 0; j < 4; ++j)
          bfr[j] = *(const short8*)(Bs + (wc * 64 + j * 16 + l15) * 64 + ch);
      }
#pragma unroll
      for (int i = 0; i < 4; ++i)
#pragma unroll
        for (int j = 0; j < 4; ++j)
          acc[i][j] = __builtin_amdgcn_mfma_f32_16x16x32_bf16(af[i], bfr[j], acc[i][j], 0, 0, 0);
    }
    __syncthreads();
  }

  // ---- Epilogue ---- (C/D frag: col = lane&15, row = (lane>>4)*4 + reg)
  if constexpr (MODE == 2) {
    // PVt: LDS-transposed epilogue [ch_local][sp_local], vector store
    // along sp (spatial at offset 0 in permuted PVt).
#pragma unroll
    for (int i = 0; i < 4; ++i)
#pragma unroll
      for (int j = 0; j < 4; ++j)
#pragma unroll
        for (int rr = 0; rr < 4; ++rr) {
          int lr2 = wc * 64 + j * 16 + ccol;            // ch-local
          int lc2 = wr * 64 + i * 16 + rgrp * 4 + rr;   // sp-local
          smem[lr2 * 128 + (lc2 ^ ((lr2 & 15) << 3))] = f2bf(acc[i][j][rr]);
        }
    __syncthreads();
    {
      int b = mt >> 3, sp0 = (mt & 7) * 128;
      int n = nt >> 2, ch0 = (nt & 3) * 128;
      long bn = b * 8 + n;
#pragma unroll
      for (int q = 0; q < 8; ++q) {
        int cid = q * 256 + tid;
        int r = cid >> 4;                 // ch-local 0..127
        int c = cid & 15;                 // sp chunk
        int pc = c ^ (r & 15);
        short8 val = *(const short8*)(smem + r * 128 + pc * 8);
        *(short8*)(g.o0 + (bn * 512 + ch0 + r) * 1088 + sp0 + c * 8) = val;
      }
    }
  } else if constexpr (MODE == 0 || MODE == 3 || MODE == 4 || MODE == 6) {
#pragma unroll
    for (int i = 0; i < 4; ++i)
#pragma unroll
      for (int j = 0; j < 4; ++j)
#pragma unroll
        for (int rr = 0; rr < 4; ++rr) {
          int lr = wr * 64 + i * 16 + rgrp * 4 + rr;
          int lc = wc * 64 + j * 16 + ccol;
          float v = acc[i][j][rr];
          if constexpr (MODE == 3) v *= 0.04419417382415922f;
          smem[lr * 128 + (lc ^ (rgrp << 4))] = f2bf(v);
        }
    __syncthreads();
#pragma unroll
    for (int q = 0; q < 8; ++q) {
      int cid = q * 256 + tid;
      int r = cid >> 4;                 // 0..127
      int c = cid & 15;                 // chunk
      int pc = c ^ ((((unsigned)r >> 2) & 3) << 1);
      short8 val = *(const short8*)(smem + r * 128 + pc * 8);
      int grow = mt * 128 + r;
      if constexpr (MODE == 0) {
        const int sec = nt >> 5;
        int b = grow >> 10, sp = grow & 1023;   // grow in 0..4095
        int gcol = (nt & 31) * 128 + c * 8;     // 0..4095 (n, ch)
        int n = gcol >> 9, ch2 = gcol & 511;
        long bn = b * 8 + n;
        if (sec == 0) {
          const float* ep = g.emb + sp * 512 + ch2;
          float4 e0 = *(const float4*)ep;
          float4 e1 = *(const float4*)(ep + 4);
          float ee[8] = {e0.x, e0.y, e0.z, e0.w, e1.x, e1.y, e1.z, e1.w};
          short8 outv;
#pragma unroll
          for (int e = 0; e < 8; ++e) outv[e] = (short)f2bf(bf2f((u16)val[e]) + ee[e]);
          *(short8*)(g.o0 + (bn * 1025 + sp) * 512 + ch2) = outv;        // PQ sp
        } else if (sec == 1) {
          *(short8*)(g.o1 + (bn * 1025 + sp) * 512 + ch2) = val;         // PK sp
        } else {
          *(short8*)(g.o2 + (bn * 1025 + 1 + sp) * 512 + ch2) = val;     // Q (orig order)
        }
      } else if constexpr (MODE == 3) {
        // interior only: grow < 1024, gcol < 1024 guaranteed
        *(short8*)(g.o0 + ((long)bz * 1025 + grow) * 1088 + nt * 128 + c * 8) = val;
      } else if constexpr (MODE == 6) {
        *(short8*)(g.o0 + ((long)(mh * 512) + grow) * 512 + nt * 128 + c * 8) = val;
      } else {  // MODE 4
        if (grow <= 1024) {
          int gcol0 = nt * 128 + c * 8;          // 0..511
          short8 outv = val;
          int l = (grow == 1024) ? 0 : grow + 1; // permuted q -> original l
          if (grow < 1024) {                     // spatial: add Q residual
            short8 rs = *(const short8*)(g.resid + ((long)gbz * 1025 + l) * 512 + gcol0);
#pragma unroll
            for (int e = 0; e < 8; ++e)
              outv[e] = (short)f2bf(bf2f((u16)val[e]) + bf2f((u16)rs[e]));
          }
          int b = gbz >> 3, n = gbz & 7;
          *(short8*)(g.o0 + (((long)b * 1025 + l) * 8 + n) * 512 + gcol0) = outv;
        }
      }
    }
  } else {
    // Scalar epilogue for mode 5 (f32 partials).
#pragma unroll
    for (int i = 0; i < 4; ++i) {
#pragma unroll
      for (int j = 0; j < 4; ++j) {
        const int gcol = nt * 128 + wc * 64 + j * 16 + ccol;
#pragma unroll
        for (int rr = 0; rr < 4; ++rr) {
          const int grow = mt * 128 + wr * 64 + i * 16 + rgrp * 4 + rr;
          if (grow < 4100)
            g.of[((long)bz * 4100 + grow) * 512 + gcol] = acc[i][j][rr];
        }
      }
    }
  }
}

// ---------------------------------------------------------------------------
extern "C" void kernel_launch(void* const* d_in, const int* in_sizes, int n_in,
                              void* d_out, int out_size, void* d_ws, size_t ws_size,
                              hipStream_t stream) {
  const float* x   = (const float*)d_in[0];
  const float* Wq  = (const float*)d_in[1];
  const float* bq  = (const float*)d_in[2];
  const float* Wk  = (const float*)d_in[3];
  const float* bk  = (const float*)d_in[4];
  const float* Wv  = (const float*)d_in[5];
  const float* bv  = (const float*)d_in[6];
  const float* Wpq = (const float*)d_in[7];
  const float* bpq = (const float*)d_in[8];
  const float* Wpk = (const float*)d_in[9];
  const float* bpk = (const float*)d_in[10];
  const float* Wpv = (const float*)d_in[11];
  const float* bpv = (const float*)d_in[12];
  const float* Wd  = (const float*)d_in[13];
  const float* bd  = (const float*)d_in[14];
  float* out = (float*)d_out;

  char* ws = (char*)d_ws;
  size_t off = 0;
  auto alloc = [&](size_t bytes) {
    char* p = ws + off;
    off += (bytes + 255) & ~(size_t)255;
    return p;
  };
  // Persistent through attention:
  u16* Wpqb = (u16*)alloc(512ull * 512 * 2);          // contiguous triple
  u16* Wpkb = (u16*)alloc(512ull * 512 * 2);
  u16* Wpvb = (u16*)alloc(512ull * 512 * 2);
  u16* Wdb  = (u16*)alloc(4096ull * 512 * 2);
  u16* Q    = (u16*)alloc(32ull * 1025 * 512 * 2);
  u16* PQ   = (u16*)alloc(32ull * 1025 * 512 * 2);   // later: 2x f32 partials
  u16* PK   = (u16*)alloc(32ull * 1025 * 512 * 2);   // later: stk (nchunk=1)
  u16* PVt  = (u16*)alloc(32ull * 512 * 1088 * 2);
  // Dead-by-attention group (S aliases from here):
  size_t s_off = off;
  u16* xb   = (u16*)alloc(4100ull * 512 * 2);
  u16* Wqb  = (u16*)alloc(4096ull * 512 * 2);   // Wqb|Wkb|Wvb contiguous
  u16* Wkb  = (u16*)alloc(4096ull * 512 * 2);
  u16* Wvb  = (u16*)alloc(4096ull * 512 * 2);
  u16* Wc   = (u16*)alloc(3ull * 4096 * 512 * 2);     // folded Wp·W
  float* bc = (float*)alloc(3ull * 4096 * 4);         // folded biases
  float* embp = (float*)alloc(1024ull * 512 * 4);
  size_t fixed_need = off;
  u16* S = (u16*)(ws + s_off);
  float* part = (float*)PQ;   // PQ dead before partials written
  (void)in_sizes; (void)n_in; (void)out_size; (void)Wkb; (void)Wvb;
  (void)Wpkb; (void)Wpvb;

  const size_t sbytes = 1025ull * 1088 * 2;
  size_t need1 = s_off + 32ull * sbytes;
  size_t need2 = s_off + 16ull * sbytes;
  size_t stk4_off = s_off + ((8ull * sbytes + 255) & ~(size_t)255);
  size_t need4 = stk4_off + 4100ull * 4096 * 2;
  int nchunk;
  u16* stk;
  if (ws_size >= need1)      { nchunk = 1; stk = PK; }   // PK dead after mode 3
  else if (ws_size >= need2 && ws_size >= fixed_need) { nchunk = 2; stk = PK; }
  else if (ws_size >= need4 && ws_size >= fixed_need) {
    nchunk = 4; stk = (u16*)(ws + stk4_off);
  } else return;  // clean fail instead of GPU fault
  if (nchunk == 2) {
    size_t stk2_off = s_off + ((16ull * sbytes + 255) & ~(size_t)255);
    if (ws_size >= stk2_off + 4100ull * 4096 * 2) stk = (u16*)(ws + stk2_off);
    else {
      nchunk = 4;
      if (ws_size >= need4) stk = (u16*)(ws + stk4_off);
      else return;
    }
  }
  int hpc = 32 / nchunk;

  // 1) dtype conversions + pos-embed (one launch)
  CvtArgs ca;
  ca.src[0] = x;   ca.dst[0] = xb;   ca.n4[0] = 4100 * 512 / 4;
  ca.src[1] = Wq;  ca.dst[1] = Wqb;  ca.n4[1] = 4096 * 512 / 4;
  ca.src[2] = Wk;  ca.dst[2] = Wkb;  ca.n4[2] = 4096 * 512 / 4;
  ca.src[3] = Wv;  ca.dst[3] = Wvb;  ca.n4[3] = 4096 * 512 / 4;
  ca.src[4] = Wpq; ca.dst[4] = Wpqb; ca.n4[4] = 512 * 512 / 4;
  ca.src[5] = Wpk; ca.dst[5] = Wpkb; ca.n4[5] = 512 * 512 / 4;
  ca.src[6] = Wpv; ca.dst[6] = Wpvb; ca.n4[6] = 512 * 512 / 4;
  ca.src[7] = Wd;  ca.dst[7] = Wdb;  ca.n4[7] = 512 * 4096 / 4;
  int total4 = 0;
  for (int s = 0; s < 8; ++s) total4 += ca.n4[s];
  int grid1 = (total4 + 1024 * 512 / 4 + 255) / 256;
  cvt_all<<<grid1, 256, 0, stream>>>(ca, total4, embp);

  // 2a) weight fold: Wc[mat][n][o][i] = sum_c Wp_mat[o][c]·W[mat*4096+n*512+c][i]
  {
    GP g = {};
    g.A = Wpqb; g.B = Wqb; g.o0 = Wc;
    gemm_bt<6><<<dim3(384, 1, 1), 256, 0, stream>>>(g);
  }
  // 2b) cls rows of PQ/PK/PVt + folded pool biases bc (wave-parallel)
  {
    CF cf;
    cf.W = Wqb; cf.Wp = Wpqb; cf.xb = xb;
    cf.bq = bq; cf.bk = bk; cf.bv = bv;
    cf.bpq = bpq; cf.bpk = bpk; cf.bpv = bpv;
    cf.PQ = PQ; cf.PK = PK; cf.PVt = PVt; cf.bc = bc;
    cls_fold<<<6144, 256, 0, stream>>>(cf);
  }

  // 3) fused projection+pool: x -> PQ(+emb) | PK | Q (spatial rows)
  {
    GP g = {};
    g.A = xb; g.B = Wc; g.B2 = Wqb;
    g.c0 = bc; g.c1 = bq; g.emb = embp;
    g.o0 = PQ; g.o1 = PK; g.o2 = Q;
    gemm_bt<0><<<dim3(96, 32, 1), 256, 0, stream>>>(g);
  }
  // 3b) PVt: x · Wc_v^T via transposed epilogue
  {
    GP g = {};
    g.A = xb; g.B = Wc + 8192 * 512; g.c0 = bc + 8192; g.o0 = PVt;
    gemm_bt<2><<<dim3(1024, 1, 1), 256, 0, stream>>>(g);
  }
  // xb, Wq/k/v, Wc, bc, embp now dead -> S aliases them.

  // 4) attention: interior S tiles + S edge -> softmax -> O (+Q resid).
  for (int c = 0; c < nchunk; ++c) {
    GP g3 = {}; g3.A = PQ; g3.B = PK; g3.o0 = S; g3.bz0 = c * hpc;
    gemm_bt<3><<<dim3(64 * hpc, 1, 1), 256, 0, stream>>>(g3);
    s_edge<<<hpc * 8, 256, 0, stream>>>(
        PQ + (long)c * hpc * 1025 * 512, PK + (long)c * hpc * 1025 * 512, S, hpc);
    softmax_rows<<<257 * hpc, 256, 0, stream>>>(S);
    GP g4 = {}; g4.A = S; g4.B = PVt; g4.resid = Q; g4.o0 = stk; g4.bz0 = c * hpc;
    gemm_bt<4><<<dim3(36 * hpc, 1, 1), 256, 0, stream>>>(g4);
  }
  // PQ dead -> 2x f32 partials alias it.

  // 5) final projection, split-K x2 -> partials, then reduce (+bias)
  {
    GP g = {}; g.A = stk; g.B = Wdb; g.of = part;
    gemm_bt<5><<<dim3(4, 33, 2), 256, 0, stream>>>(g);
  }
  reduce2<<<(4100 * 512 / 4 + 255) / 256, 256, 0, stream>>>(part, bd, out);
}